// Round 8
// baseline (672.780 us; speedup 1.0000x reference)
//
#include <hip/hip_runtime.h>
#include <math.h>

// Problem constants
#define T_TOK   4096            // B*S
#define D_MODEL 768
#define H_HEADS 12
#define HDIM    64
#define S_SEQ   512
#define B_BATCH 8
#define E_EXP   8
#define FF_DIM  3072
#define MAX_TILES 40            // worst-case sum ceil(c_e/128)
#define MPAD_MAX  (MAX_TILES * 128)   // 5120
#define KSPLIT  4               // split-K factor for MoE down-GEMM

typedef __attribute__((ext_vector_type(8))) short short8;
typedef __attribute__((ext_vector_type(4))) float floatx4;

__device__ __forceinline__ float gelu_exact(float x) {
    return 0.5f * x * (1.0f + erff(x * 0.7071067811865476f));
}

// fp32 -> bf16 round-to-nearest-even
__device__ __forceinline__ unsigned short f2bf(float f) {
    unsigned int u = __float_as_uint(f);
    u += 0x7fffu + ((u >> 16) & 1u);
    return (unsigned short)(u >> 16);
}
__device__ __forceinline__ float bf2f(unsigned short h) {
    return __uint_as_float(((unsigned int)h) << 16);
}
// exact two-term bf16 split: v ~= hi + lo, |v-hi-lo| <= 2^-18 |v|
__device__ __forceinline__ void split_bf(float v, unsigned short& hi, unsigned short& lo) {
    hi = f2bf(v);
    lo = f2bf(v - bf2f(hi));
}

// async global->LDS, 16 B per lane, wave-uniform LDS base (+lane*16 implicit)
__device__ __forceinline__ void gload16(const void* g, void* l) {
    __builtin_amdgcn_global_load_lds(
        (const __attribute__((address_space(1))) unsigned int*)g,
        (__attribute__((address_space(3))) unsigned int*)l, 16, 0, 0);
}
// 16B-slot swizzle for [*][32]-short (64 B row) LDS tiles; period 16 rows.
// Staging invariant: LDS[r][s] = G[r][s ^ swz3(r)]; read XORs the same value
// back out (rule #21 both-sides-or-neither). Bank-uniform on ds_read_b128.
__device__ __forceinline__ int swz3(int r) { return (r ^ (r >> 2)) & 3; }

// ---------------- LayerNorm fp32-out ----------------
__global__ void __launch_bounds__(256) ln_f32(const float* __restrict__ x,
                                              const float* __restrict__ g,
                                              const float* __restrict__ b,
                                              float* __restrict__ out) {
    int row = blockIdx.x;
    const float* xr = x + (size_t)row * D_MODEL;
    int tid = threadIdx.x;
    float v0 = xr[tid], v1 = xr[tid + 256], v2 = xr[tid + 512];
    float s = v0 + v1 + v2;
    float q = v0 * v0 + v1 * v1 + v2 * v2;
    for (int off = 32; off; off >>= 1) {
        s += __shfl_down(s, off);
        q += __shfl_down(q, off);
    }
    __shared__ float rs[4], rq[4], stats[2];
    int wid = tid >> 6, lane = tid & 63;
    if (lane == 0) { rs[wid] = s; rq[wid] = q; }
    __syncthreads();
    if (tid == 0) {
        float ts = rs[0] + rs[1] + rs[2] + rs[3];
        float tq = rq[0] + rq[1] + rq[2] + rq[3];
        float mu = ts * (1.0f / 768.0f);
        float var = tq * (1.0f / 768.0f) - mu * mu;
        stats[0] = mu; stats[1] = rsqrtf(var + 1e-5f);
    }
    __syncthreads();
    float mu = stats[0], rstd = stats[1];
    float* orow = out + (size_t)row * D_MODEL;
    orow[tid]       = (v0 - mu) * rstd * g[tid]       + b[tid];
    orow[tid + 256] = (v1 - mu) * rstd * g[tid + 256] + b[tid + 256];
    orow[tid + 512] = (v2 - mu) * rstd * g[tid + 512] + b[tid + 512];
}

// ---------------- LayerNorm split-bf16-out ----------------
__global__ void __launch_bounds__(256) ln_split(const float* __restrict__ x,
                                                const float* __restrict__ g,
                                                const float* __restrict__ b,
                                                unsigned short* __restrict__ ohi,
                                                unsigned short* __restrict__ olo) {
    int row = blockIdx.x;
    const float* xr = x + (size_t)row * D_MODEL;
    int tid = threadIdx.x;
    float v0 = xr[tid], v1 = xr[tid + 256], v2 = xr[tid + 512];
    float s = v0 + v1 + v2;
    float q = v0 * v0 + v1 * v1 + v2 * v2;
    for (int off = 32; off; off >>= 1) {
        s += __shfl_down(s, off);
        q += __shfl_down(q, off);
    }
    __shared__ float rs[4], rq[4], stats[2];
    int wid = tid >> 6, lane = tid & 63;
    if (lane == 0) { rs[wid] = s; rq[wid] = q; }
    __syncthreads();
    if (tid == 0) {
        float ts = rs[0] + rs[1] + rs[2] + rs[3];
        float tq = rq[0] + rq[1] + rq[2] + rq[3];
        float mu = ts * (1.0f / 768.0f);
        float var = tq * (1.0f / 768.0f) - mu * mu;
        stats[0] = mu; stats[1] = rsqrtf(var + 1e-5f);
    }
    __syncthreads();
    float mu = stats[0], rstd = stats[1];
    unsigned short* hr = ohi + (size_t)row * D_MODEL;
    unsigned short* lr = olo + (size_t)row * D_MODEL;
    float r0 = (v0 - mu) * rstd * g[tid]       + b[tid];
    float r1 = (v1 - mu) * rstd * g[tid + 256] + b[tid + 256];
    float r2 = (v2 - mu) * rstd * g[tid + 512] + b[tid + 512];
    unsigned short hi, lo;
    split_bf(r0, hi, lo); hr[tid] = hi;       lr[tid] = lo;
    split_bf(r1, hi, lo); hr[tid + 256] = hi; lr[tid + 256] = lo;
    split_bf(r2, hi, lo); hr[tid + 512] = hi; lr[tid + 512] = lo;
}

// ---------------- Weight transpose fp32 -> bf16 (single) ----------------
__global__ void __launch_bounds__(256) transpose_bf16(const float* __restrict__ in,
                                                      unsigned short* __restrict__ out,
                                                      int R, int C) {
    __shared__ float t[32][33];
    const float* inb = in + (size_t)blockIdx.z * R * C;
    unsigned short* outb = out + (size_t)blockIdx.z * R * C;
    int c0 = blockIdx.x * 32, r0 = blockIdx.y * 32;
    int tx = threadIdx.x & 31, ty = threadIdx.x >> 5;
#pragma unroll
    for (int rr = 0; rr < 32; rr += 8)
        t[ty + rr][tx] = inb[(size_t)(r0 + ty + rr) * C + c0 + tx];
    __syncthreads();
#pragma unroll
    for (int rr = 0; rr < 32; rr += 8)
        outb[(size_t)(c0 + ty + rr) * R + r0 + tx] = f2bf(t[tx][ty + rr]);
}

// ---------------- Weight transpose fp32 -> split bf16 (hi+lo) -------------
__global__ void __launch_bounds__(256) transpose_split(const float* __restrict__ in,
                                                       unsigned short* __restrict__ out_hi,
                                                       unsigned short* __restrict__ out_lo,
                                                       int R, int C) {
    __shared__ float t[32][33];
    int c0 = blockIdx.x * 32, r0 = blockIdx.y * 32;
    int tx = threadIdx.x & 31, ty = threadIdx.x >> 5;
#pragma unroll
    for (int rr = 0; rr < 32; rr += 8)
        t[ty + rr][tx] = in[(size_t)(r0 + ty + rr) * C + c0 + tx];
    __syncthreads();
#pragma unroll
    for (int rr = 0; rr < 32; rr += 8) {
        float v = t[tx][ty + rr];
        unsigned short hi, lo;
        split_bf(v, hi, lo);
        size_t idx = (size_t)(c0 + ty + rr) * R + r0 + tx;
        out_hi[idx] = hi;
        out_lo[idx] = lo;
    }
}

// ---------------- MFMA flash attention (split-bf16, fp32-class accuracy) --
__global__ void __launch_bounds__(256) attn_mfma(const float* __restrict__ qkv,
                                                 unsigned short* __restrict__ ohi,
                                                 unsigned short* __restrict__ olo) {
    __shared__ __align__(16) short Kh[64][72], Kl[64][72];   // S: K ; PV: P
    __shared__ __align__(16) short Vh[64][72], Vl[64][72];   // V^T: [d][key]

    int qt = blockIdx.x, hh = blockIdx.y, bb = blockIdx.z;
    int tid = threadIdx.x;
    int lane = tid & 63, wv = tid >> 6;
    int lm = lane & 15, q8 = (lane >> 4) * 8, q4 = (lane >> 4) * 4;
    const size_t rstride = 3 * D_MODEL;
    const float* base = qkv + (size_t)bb * S_SEQ * rstride + hh * HDIM;

    // --- Q A-frags (scaled 1/8, split) directly global->registers ---
    short8 qh[2], ql[2];
    {
        const float* qrow = base + (size_t)(qt * 64 + 16 * wv + lm) * rstride;
#pragma unroll
        for (int ks = 0; ks < 2; ks++) {
            float4 v0 = *(const float4*)(qrow + ks * 32 + q8);
            float4 v1 = *(const float4*)(qrow + ks * 32 + q8 + 4);
            unsigned short h_, l_;
            short8 sh, sl;
            split_bf(v0.x * 0.125f, h_, l_); sh[0] = (short)h_; sl[0] = (short)l_;
            split_bf(v0.y * 0.125f, h_, l_); sh[1] = (short)h_; sl[1] = (short)l_;
            split_bf(v0.z * 0.125f, h_, l_); sh[2] = (short)h_; sl[2] = (short)l_;
            split_bf(v0.w * 0.125f, h_, l_); sh[3] = (short)h_; sl[3] = (short)l_;
            split_bf(v1.x * 0.125f, h_, l_); sh[4] = (short)h_; sl[4] = (short)l_;
            split_bf(v1.y * 0.125f, h_, l_); sh[5] = (short)h_; sl[5] = (short)l_;
            split_bf(v1.z * 0.125f, h_, l_); sh[6] = (short)h_; sl[6] = (short)l_;
            split_bf(v1.w * 0.125f, h_, l_); sh[7] = (short)h_; sl[7] = (short)l_;
            qh[ks] = sh; ql[ks] = sl;
        }
    }

    float m_run[4], l_run[4];
    floatx4 o_acc[4];
#pragma unroll
    for (int i = 0; i < 4; i++) {
        m_run[i] = -1e30f; l_run[i] = 0.f;
        o_acc[i] = (floatx4){0.f, 0.f, 0.f, 0.f};
    }

    int sr = tid >> 2;              // staging row 0..63
    int sc0 = (tid & 3) * 16;       // staging dim block

    for (int kt = 0; kt < 8; kt++) {
        __syncthreads();   // A: prev PV frag reads done
        {
            const float* krow = base + (size_t)(kt * 64 + sr) * rstride + D_MODEL;
            const float* vrow = krow + D_MODEL;
#pragma unroll
            for (int c = 0; c < 16; c += 4) {
                float4 kv = *(const float4*)(krow + sc0 + c);
                ushort4 h4, l4; unsigned short h_, l_;
                split_bf(kv.x, h_, l_); h4.x = h_; l4.x = l_;
                split_bf(kv.y, h_, l_); h4.y = h_; l4.y = l_;
                split_bf(kv.z, h_, l_); h4.z = h_; l4.z = l_;
                split_bf(kv.w, h_, l_); h4.w = h_; l4.w = l_;
                *(ushort4*)&Kh[sr][sc0 + c] = h4;
                *(ushort4*)&Kl[sr][sc0 + c] = l4;
                float4 vv = *(const float4*)(vrow + sc0 + c);
                split_bf(vv.x, h_, l_); Vh[sc0 + c + 0][sr] = (short)h_; Vl[sc0 + c + 0][sr] = (short)l_;
                split_bf(vv.y, h_, l_); Vh[sc0 + c + 1][sr] = (short)h_; Vl[sc0 + c + 1][sr] = (short)l_;
                split_bf(vv.z, h_, l_); Vh[sc0 + c + 2][sr] = (short)h_; Vl[sc0 + c + 2][sr] = (short)l_;
                split_bf(vv.w, h_, l_); Vh[sc0 + c + 3][sr] = (short)h_; Vl[sc0 + c + 3][sr] = (short)l_;
            }
        }
        __syncthreads();   // B: staging visible

        // S = Q @ K^T (3-term split)
        floatx4 s_acc[4];
#pragma unroll
        for (int nt = 0; nt < 4; nt++) s_acc[nt] = (floatx4){0.f, 0.f, 0.f, 0.f};
#pragma unroll
        for (int ks = 0; ks < 2; ks++) {
#pragma unroll
            for (int nt = 0; nt < 4; nt++) {
                short8 bh = *(const short8*)&Kh[nt * 16 + lm][ks * 32 + q8];
                short8 bl = *(const short8*)&Kl[nt * 16 + lm][ks * 32 + q8];
                s_acc[nt] = __builtin_amdgcn_mfma_f32_16x16x32_bf16(qh[ks], bh, s_acc[nt], 0, 0, 0);
                s_acc[nt] = __builtin_amdgcn_mfma_f32_16x16x32_bf16(qh[ks], bl, s_acc[nt], 0, 0, 0);
                s_acc[nt] = __builtin_amdgcn_mfma_f32_16x16x32_bf16(ql[ks], bh, s_acc[nt], 0, 0, 0);
            }
        }

        // Online softmax (C-layout: col=lane&15, row=q4+reg; row reduce = 16-lane quad)
        float alpha_r[4];
#pragma unroll
        for (int reg = 0; reg < 4; reg++) {
            float tm = fmaxf(fmaxf(s_acc[0][reg], s_acc[1][reg]),
                             fmaxf(s_acc[2][reg], s_acc[3][reg]));
            tm = fmaxf(tm, __shfl_xor(tm, 1));
            tm = fmaxf(tm, __shfl_xor(tm, 2));
            tm = fmaxf(tm, __shfl_xor(tm, 4));
            tm = fmaxf(tm, __shfl_xor(tm, 8));
            float mn = fmaxf(m_run[reg], tm);
            alpha_r[reg] = __expf(m_run[reg] - mn);
            m_run[reg] = mn;
            float ts = 0.f;
#pragma unroll
            for (int nt = 0; nt < 4; nt++) {
                float pv = __expf(s_acc[nt][reg] - mn);
                s_acc[nt][reg] = pv;
                ts += pv;
            }
            ts += __shfl_xor(ts, 1);
            ts += __shfl_xor(ts, 2);
            ts += __shfl_xor(ts, 4);
            ts += __shfl_xor(ts, 8);
            l_run[reg] = l_run[reg] * alpha_r[reg] + ts;
        }

        __syncthreads();   // C: all S frag reads of Kh/Kl retired -> safe to overwrite as P

        // P (split) into the K buffers: P[row][key]
#pragma unroll
        for (int nt = 0; nt < 4; nt++)
#pragma unroll
            for (int reg = 0; reg < 4; reg++) {
                unsigned short h_, l_;
                split_bf(s_acc[nt][reg], h_, l_);
                Kh[16 * wv + q4 + reg][nt * 16 + lm] = (short)h_;
                Kl[16 * wv + q4 + reg][nt * 16 + lm] = (short)l_;
            }
        // rescale O accumulator
#pragma unroll
        for (int nt = 0; nt < 4; nt++)
#pragma unroll
            for (int reg = 0; reg < 4; reg++) o_acc[nt][reg] *= alpha_r[reg];

        __syncthreads();   // D: P visible

        // O += P @ V (3-term split); A = P[m][key], B = V^T[d][key] n-major
#pragma unroll
        for (int ks = 0; ks < 2; ks++) {
            short8 ph = *(const short8*)&Kh[16 * wv + lm][ks * 32 + q8];
            short8 pl = *(const short8*)&Kl[16 * wv + lm][ks * 32 + q8];
#pragma unroll
            for (int nt = 0; nt < 4; nt++) {
                short8 vh = *(const short8*)&Vh[nt * 16 + lm][ks * 32 + q8];
                short8 vl = *(const short8*)&Vl[nt * 16 + lm][ks * 32 + q8];
                o_acc[nt] = __builtin_amdgcn_mfma_f32_16x16x32_bf16(ph, vh, o_acc[nt], 0, 0, 0);
                o_acc[nt] = __builtin_amdgcn_mfma_f32_16x16x32_bf16(ph, vl, o_acc[nt], 0, 0, 0);
                o_acc[nt] = __builtin_amdgcn_mfma_f32_16x16x32_bf16(pl, vh, o_acc[nt], 0, 0, 0);
            }
        }
    }

    // Epilogue: O/l -> split hi/lo (C-layout scatter)
    size_t ob = (size_t)(bb * S_SEQ + qt * 64) * D_MODEL + hh * HDIM;
#pragma unroll
    for (int reg = 0; reg < 4; reg++) {
        float inv = 1.0f / l_run[reg];
#pragma unroll
        for (int nt = 0; nt < 4; nt++) {
            unsigned short h_, l_;
            split_bf(o_acc[nt][reg] * inv, h_, l_);
            size_t idx = ob + (size_t)(16 * wv + q4 + reg) * D_MODEL + nt * 16 + lm;
            ohi[idx] = h_;
            olo[idx] = l_;
        }
    }
}

// ---------------- Router (fp32, exact — unchanged) -------------
__global__ void __launch_bounds__(64) router_kernel(const float* __restrict__ h2,
                                                    const float* __restrict__ sw,
                                                    const float* __restrict__ sb,
                                                    int* __restrict__ routes,
                                                    int* __restrict__ counts) {
    int t = blockIdx.x;
    int lane = threadIdx.x;
    const float* hr = h2 + (size_t)t * D_MODEL;
    float acc[8] = {};
    for (int d = lane; d < D_MODEL; d += 64) {
        float hv = hr[d];
        const float* wr = sw + (size_t)d * 8;
#pragma unroll
        for (int e = 0; e < 8; e++) acc[e] += hv * wr[e];
    }
#pragma unroll
    for (int e = 0; e < 8; e++)
        for (int off = 32; off; off >>= 1) acc[e] += __shfl_down(acc[e], off);
    if (lane == 0) {
        int best = 0;
        float bv = acc[0] + sb[0];
#pragma unroll
        for (int e = 1; e < 8; e++) {
            float v = acc[e] + sb[e];
            if (v > bv) { bv = v; best = e; }
        }
        routes[t] = best;
        atomicAdd(&counts[best], 1);
    }
}

__global__ void __launch_bounds__(256) init_kernel(int* counts, int* cursor, int* perm) {
    int idx = blockIdx.x * 256 + threadIdx.x;
    if (idx < MPAD_MAX) perm[idx] = -1;
    if (idx < 8) { counts[idx] = 0; cursor[idx] = 0; }
}

// zero the split-K partial accumulator (fp32, MPAD_MAX x D_MODEL)
__global__ void __launch_bounds__(256) zero_tmp(float* __restrict__ t) {
    size_t i = ((size_t)blockIdx.x * 256 + threadIdx.x) * 4;
    if (i < (size_t)MPAD_MAX * D_MODEL)
        *(float4*)(t + i) = (float4){0.f, 0.f, 0.f, 0.f};
}

__global__ void moe_plan(const int* __restrict__ counts, int* pad_base,
                         int* tile_e, int* tile_row0, int* ntiles) {
    if (threadIdx.x == 0 && blockIdx.x == 0) {
        int base = 0, nt = 0;
        for (int e = 0; e < E_EXP; e++) {
            pad_base[e] = base;
            int c = counts[e];
            int nte = (c + 127) >> 7;
            for (int j = 0; j < nte; j++) {
                tile_e[nt] = e;
                tile_row0[nt] = base + j * 128;
                nt++;
            }
            base += nte * 128;
        }
        ntiles[0] = nt;
    }
}

__global__ void __launch_bounds__(256) scatter_kernel(const int* __restrict__ routes,
                                                      const int* __restrict__ pad_base,
                                                      int* __restrict__ cursor,
                                                      int* __restrict__ perm) {
    int t = blockIdx.x * 256 + threadIdx.x;
    if (t < T_TOK) {
        int e = routes[t];
        int pos = atomicAdd(&cursor[e], 1);
        perm[pad_base[e] + pos] = t;
    }
}

__global__ void __launch_bounds__(256) gather_bf16(const float* __restrict__ h2,
                                                   const int* __restrict__ perm,
                                                   unsigned short* __restrict__ Ag) {
    int g = blockIdx.x;
    int row = perm[g];
    unsigned short* dst = Ag + (size_t)g * D_MODEL;
    if (row >= 0) {
        const float* src = h2 + (size_t)row * D_MODEL;
        for (int d = threadIdx.x; d < D_MODEL; d += 256) dst[d] = f2bf(src[d]);
    } else {
        for (int d = threadIdx.x; d < D_MODEL; d += 256) dst[d] = 0;
    }
}

// ---------------- split-bf16 MFMA GEMM (fp32-class accuracy) ---------------
// 2-phase double-buffered pipeline (T3 minimum): issue next K-step's
// global_load_lds BEFORE computing current step; ONE barrier per step so the
// compiler's vmcnt(0) drain lands after compute (loads fly under MFMA).
// BK=32; LDS 2x(4x8KB)=64KB -> 2 blocks/CU cap.
// MODE 0: Cf = A@B            MODE 1: Cf = resid + A@B + bias
template <int MODE>
__global__ void __launch_bounds__(256) sgemm(const unsigned short* __restrict__ Ah_,
                                             const unsigned short* __restrict__ Al_,
                                             const unsigned short* __restrict__ Bh_,
                                             const unsigned short* __restrict__ Bl_,
                                             const float* __restrict__ bias,
                                             const float* __restrict__ resid,
                                             float* __restrict__ Cf,
                                             int N, int K) {
    __shared__ __align__(16) short Ah[2][128][32];
    __shared__ __align__(16) short Al[2][128][32];
    __shared__ __align__(16) short Bh[2][128][32];
    __shared__ __align__(16) short Bl[2][128][32];

    int row0 = blockIdx.y * 128, n0 = blockIdx.x * 128;
    int tid = threadIdx.x;
    int lane = tid & 63, wid = tid >> 6;
    int wr0 = (wid >> 1) * 64, wc0 = (wid & 1) * 64;
    int lm = lane & 15, q8 = (lane >> 4) * 8;

    // staging geometry: wave wid owns rows [32*wid, 32*wid+32), 2 chunks of
    // 16 rows. Lane: row = chunk*16 + l>>2, dest slot l&3, src slot ^swz3(r).
    int rch = lane >> 2, sl = lane & 3;
    int rst = wid * 32 + rch;
    int gsb = (sl ^ swz3(rst)) << 4;

    const unsigned short* Ahb = Ah_ + (size_t)row0 * K;
    const unsigned short* Alb = Al_ + (size_t)row0 * K;
    const unsigned short* Bhb = Bh_ + (size_t)n0 * K;
    const unsigned short* Blb = Bl_ + (size_t)n0 * K;

    const char* gAh = (const char*)(Ahb + (size_t)rst * K) + gsb;
    const char* gAl = (const char*)(Alb + (size_t)rst * K) + gsb;
    const char* gBh = (const char*)(Bhb + (size_t)rst * K) + gsb;
    const char* gBl = (const char*)(Blb + (size_t)rst * K) + gsb;
    size_t r16 = (size_t)16 * K * 2;   // +16 rows, bytes

    auto stage = [&](int b, int t) {
        size_t kb = (size_t)t * 64;    // t*32 shorts * 2B
        gload16(gAh + kb,       &Ah[b][wid * 32][0]);
        gload16(gAh + r16 + kb, &Ah[b][wid * 32 + 16][0]);
        gload16(gAl + kb,       &Al[b][wid * 32][0]);
        gload16(gAl + r16 + kb, &Al[b][wid * 32 + 16][0]);
        gload16(gBh + kb,       &Bh[b][wid * 32][0]);
        gload16(gBh + r16 + kb, &Bh[b][wid * 32 + 16][0]);
        gload16(gBl + kb,       &Bl[b][wid * 32][0]);
        gload16(gBl + r16 + kb, &Bl[b][wid * 32 + 16][0]);
    };

    floatx4 acc[4][4];
#pragma unroll
    for (int i = 0; i < 4; i++)
#pragma unroll
        for (int j = 0; j < 4; j++) acc[i][j] = (floatx4){0.f, 0.f, 0.f, 0.f};

    const int NSTEP = K >> 5;
    stage(0, 0);
    __syncthreads();   // prologue drain: buf0 ready

    int cur = 0;
    for (int t = 0; t < NSTEP; t++) {
        if (t + 1 < NSTEP) stage(cur ^ 1, t + 1);   // prefetch flies under compute

        short8 ah[4], al[4], bh[4], bl[4];
#pragma unroll
        for (int i = 0; i < 4; i++) {
            int r = wr0 + i * 16 + lm;
            int bo = (q8 * 2) ^ (swz3(r) << 4);
            ah[i] = *(const short8*)((const char*)&Ah[cur][r][0] + bo);
            al[i] = *(const short8*)((const char*)&Al[cur][r][0] + bo);
        }
#pragma unroll
        for (int j = 0; j < 4; j++) {
            int r = wc0 + j * 16 + lm;
            int bo = (q8 * 2) ^ (swz3(r) << 4);
            bh[j] = *(const short8*)((const char*)&Bh[cur][r][0] + bo);
            bl[j] = *(const short8*)((const char*)&Bl[cur][r][0] + bo);
        }
#pragma unroll
        for (int i = 0; i < 4; i++)
#pragma unroll
            for (int j = 0; j < 4; j++) {
                acc[i][j] = __builtin_amdgcn_mfma_f32_16x16x32_bf16(ah[i], bh[j], acc[i][j], 0, 0, 0);
                acc[i][j] = __builtin_amdgcn_mfma_f32_16x16x32_bf16(ah[i], bl[j], acc[i][j], 0, 0, 0);
                acc[i][j] = __builtin_amdgcn_mfma_f32_16x16x32_bf16(al[i], bh[j], acc[i][j], 0, 0, 0);
            }
        __syncthreads();   // one barrier/step: drains prefetch + retires ds_reads
        cur ^= 1;
    }

    int q4 = (lane >> 4) * 4;
#pragma unroll
    for (int i = 0; i < 4; i++) {
#pragma unroll
        for (int j = 0; j < 4; j++) {
            int c = n0 + wc0 + j * 16 + lm;
#pragma unroll
            for (int reg = 0; reg < 4; reg++) {
                int rloc = wr0 + i * 16 + q4 + reg;
                size_t idx = (size_t)(row0 + rloc) * N + c;
                float v = acc[i][j][reg];
                if constexpr (MODE == 0) Cf[idx] = v;
                else                     Cf[idx] = resid[idx] + v + bias[c];
            }
        }
    }
}

// ---------------- bf16 MFMA GEMM (MoE up) ----------------------------------
// 2-phase double-buffered, BK=64. LDS rows are 128B: swizzle slot ^= (r&7);
// staging: linear dest + inverse-swizzled source (src slot = (l&7)^(l>>3)).
// LDS 2x2x16KB = 64KB. MODE 2: Cb = bf16(gelu(A@B + bias))
template <int MODE>
__global__ void __launch_bounds__(256) mgemm(const unsigned short* __restrict__ A,
                                             const unsigned short* __restrict__ Bt,
                                             const float* __restrict__ bias,
                                             const float* __restrict__ resid,
                                             float* __restrict__ Cf,
                                             unsigned short* __restrict__ Cb,
                                             int N, int K,
                                             const int* __restrict__ perm,
                                             const int* __restrict__ tile_e,
                                             const int* __restrict__ tile_row0,
                                             const int* __restrict__ ntiles) {
    __shared__ __align__(16) short As[2][128][64];
    __shared__ __align__(16) short Bs[2][128][64];

    if ((int)blockIdx.y >= ntiles[0]) return;
    int e = tile_e[blockIdx.y];
    int row0 = tile_row0[blockIdx.y];
    Bt += (size_t)e * N * K;
    bias += (size_t)e * N;
    int n0 = blockIdx.x * 128;

    int tid = threadIdx.x;
    int lane = tid & 63, wid = tid >> 6;
    int wr0 = (wid >> 1) * 64, wc0 = (wid & 1) * 64;
    int lm = lane & 15, q8 = (lane >> 4) * 8;

    int rl = lane >> 3, sl = lane & 7;
    int gsb = (sl ^ rl) << 4;

    const unsigned short* Abase = A + (size_t)row0 * K;
    const unsigned short* Bbase = Bt + (size_t)n0 * K;
    const char* gA = (const char*)(Abase + (size_t)(wid * 32 + rl) * K) + gsb;
    const char* gB = (const char*)(Bbase + (size_t)(wid * 32 + rl) * K) + gsb;

    auto stage = [&](int b, int t) {
        size_t kb = (size_t)t * 128;   // t*64 shorts * 2B
#pragma unroll
        for (int c = 0; c < 4; c++) {
            gload16(gA + (size_t)c * 16 * K + kb, &As[b][wid * 32 + c * 8][0]);
            gload16(gB + (size_t)c * 16 * K + kb, &Bs[b][wid * 32 + c * 8][0]);
        }
    };

    floatx4 acc[4][4];
#pragma unroll
    for (int i = 0; i < 4; i++)
#pragma unroll
        for (int j = 0; j < 4; j++) acc[i][j] = (floatx4){0.f, 0.f, 0.f, 0.f};

    const int NSTEP = K >> 6;
    stage(0, 0);
    __syncthreads();

    int cur = 0;
    for (int t = 0; t < NSTEP; t++) {
        if (t + 1 < NSTEP) stage(cur ^ 1, t + 1);

#pragma unroll
        for (int ks = 0; ks < 2; ks++) {
            short8 af[4], bfr[4];
#pragma unroll
            for (int i = 0; i < 4; i++) {
                int r = wr0 + i * 16 + lm;
                int bo = (ks * 64 + q8 * 2) ^ ((r & 7) << 4);
                af[i] = *(const short8*)((const char*)&As[cur][r][0] + bo);
            }
#pragma unroll
            for (int j = 0; j < 4; j++) {
                int r = wc0 + j * 16 + lm;
                int bo = (ks * 64 + q8 * 2) ^ ((r & 7) << 4);
                bfr[j] = *(const short8*)((const char*)&Bs[cur][r][0] + bo);
            }
#pragma unroll
            for (int i = 0; i < 4; i++)
#pragma unroll
                for (int j = 0; j < 4; j++)
                    acc[i][j] = __builtin_amdgcn_mfma_f32_16x16x32_bf16(af[i], bfr[j], acc[i][j], 0, 0, 0);
        }
        __syncthreads();
        cur ^= 1;
    }

    int q4 = (lane >> 4) * 4;
#pragma unroll
    for (int i = 0; i < 4; i++) {
#pragma unroll
        for (int j = 0; j < 4; j++) {
            int c = n0 + wc0 + j * 16 + lm;
#pragma unroll
            for (int reg = 0; reg < 4; reg++) {
                int rloc = wr0 + i * 16 + q4 + reg;
                float v = acc[i][j][reg];
                if constexpr (MODE == 2) {
                    Cb[(size_t)(row0 + rloc) * N + c] = f2bf(gelu_exact(v + bias[c]));
                } else {
                    int t = perm[row0 + rloc];
                    if (t >= 0) {
                        size_t idx = (size_t)t * N + c;
                        Cf[idx] = resid[idx] + gelu_exact(v + bias[c]);
                    }
                }
            }
        }
    }
}

// ---------------- bf16 MFMA GEMM, split-K (MoE down partial) ---------------
// Same structure as mgemm but grid.z = KSPLIT K-slices; each block computes a
// fp32 partial of A@Bt over K/KSPLIT and atomicAdds into tmp[padded_row][c].
// gelu/bias/residual deferred to moe_epilogue (nonlinear => after full sum).
__global__ void __launch_bounds__(256) kgemm(const unsigned short* __restrict__ A,
                                             const unsigned short* __restrict__ Bt,
                                             float* __restrict__ tmp,
                                             int N, int K,
                                             const int* __restrict__ tile_e,
                                             const int* __restrict__ tile_row0,
                                             const int* __restrict__ ntiles) {
    __shared__ __align__(16) short As[2][128][64];
    __shared__ __align__(16) short Bs[2][128][64];

    if ((int)blockIdx.y >= ntiles[0]) return;
    int e = tile_e[blockIdx.y];
    int row0 = tile_row0[blockIdx.y];
    Bt += (size_t)e * N * K;
    int n0 = blockIdx.x * 128;
    const int KLEN = K / KSPLIT;                 // 768
    size_t kbase = (size_t)blockIdx.z * KLEN * 2;  // byte offset of this K-slice

    int tid = threadIdx.x;
    int lane = tid & 63, wid = tid >> 6;
    int wr0 = (wid >> 1) * 64, wc0 = (wid & 1) * 64;
    int lm = lane & 15, q8 = (lane >> 4) * 8;

    int rl = lane >> 3, sl = lane & 7;
    int gsb = (sl ^ rl) << 4;

    const unsigned short* Abase = A + (size_t)row0 * K;
    const unsigned short* Bbase = Bt + (size_t)n0 * K;
    const char* gA = (const char*)(Abase + (size_t)(wid * 32 + rl) * K) + gsb + kbase;
    const char* gB = (const char*)(Bbase + (size_t)(wid * 32 + rl) * K) + gsb + kbase;

    auto stage = [&](int b, int t) {
        size_t kb = (size_t)t * 128;
#pragma unroll
        for (int c = 0; c < 4; c++) {
            gload16(gA + (size_t)c * 16 * K + kb, &As[b][wid * 32 + c * 8][0]);
            gload16(gB + (size_t)c * 16 * K + kb, &Bs[b][wid * 32 + c * 8][0]);
        }
    };

    floatx4 acc[4][4];
#pragma unroll
    for (int i = 0; i < 4; i++)
#pragma unroll
        for (int j = 0; j < 4; j++) acc[i][j] = (floatx4){0.f, 0.f, 0.f, 0.f};

    const int NSTEP = KLEN >> 6;                 // 12
    stage(0, 0);
    __syncthreads();

    int cur = 0;
    for (int t = 0; t < NSTEP; t++) {
        if (t + 1 < NSTEP) stage(cur ^ 1, t + 1);

#pragma unroll
        for (int ks = 0; ks < 2; ks++) {
            short8 af[4], bfr[4];
#pragma unroll
            for (int i = 0; i < 4; i++) {
                int r = wr0 + i * 16 + lm;
                int bo = (ks * 64 + q8 * 2) ^ ((r & 7) << 4);
                af[i] = *(const short8*)((const char*)&As[cur][r][0] + bo);
            }
#pragma unroll
            for (int j = 0; j < 4; j++) {
                int r = wc0 + j * 16 + lm;
                int bo = (ks * 64 + q8 * 2) ^ ((r & 7) << 4);
                bfr[j] = *(const short8*)((const char*)&Bs[cur][r][0] + bo);
            }
#pragma unroll
            for (int i = 0; i < 4; i++)
#pragma unroll
                for (int j = 0; j < 4; j++)
                    acc[i][j] = __builtin_amdgcn_mfma_f32_16x16x32_bf16(af[i], bfr[j], acc[i][j], 0, 0, 0);
        }
        __syncthreads();
        cur ^= 1;
    }

    int q4 = (lane >> 4) * 4;
#pragma unroll
    for (int i = 0; i < 4; i++) {
#pragma unroll
        for (int j = 0; j < 4; j++) {
            int c = n0 + wc0 + j * 16 + lm;
#pragma unroll
            for (int reg = 0; reg < 4; reg++) {
                int rloc = wr0 + i * 16 + q4 + reg;
                atomicAdd(&tmp[(size_t)(row0 + rloc) * N + c], acc[i][j][reg]);
            }
        }
    }
}

// ---------------- MoE down epilogue: out = x1 + gelu(tmp + b2[route]) ------
__global__ void __launch_bounds__(256) moe_epilogue(const float* __restrict__ tmp,
                                                    const int* __restrict__ perm,
                                                    const int* __restrict__ routes,
                                                    const float* __restrict__ b2,
                                                    const float* __restrict__ x1,
                                                    float* __restrict__ out) {
    int g = blockIdx.x;
    int t = perm[g];
    if (t < 0) return;
    int e = routes[t];
    const float* tr = tmp + (size_t)g * D_MODEL;
    const float* br = b2 + (size_t)e * D_MODEL;
    const float* xr = x1 + (size_t)t * D_MODEL;
    float* orow = out + (size_t)t * D_MODEL;
    int d = threadIdx.x;
    orow[d]       = xr[d]       + gelu_exact(tr[d]       + br[d]);
    orow[d + 256] = xr[d + 256] + gelu_exact(tr[d + 256] + br[d + 256]);
    orow[d + 512] = xr[d + 512] + gelu_exact(tr[d + 512] + br[d + 512]);
}

extern "C" void kernel_launch(void* const* d_in, const int* in_sizes, int n_in,
                              void* d_out, int out_size, void* d_ws, size_t ws_size,
                              hipStream_t stream) {
    const float* x      = (const float*)d_in[0];
    const float* ln1_g  = (const float*)d_in[2];
    const float* ln1_b  = (const float*)d_in[3];
    const float* qkv_w  = (const float*)d_in[4];
    const float* proj_w = (const float*)d_in[5];
    const float* proj_b = (const float*)d_in[6];
    const float* ln2_g  = (const float*)d_in[7];
    const float* ln2_b  = (const float*)d_in[8];
    const float* sw     = (const float*)d_in[9];
    const float* sb     = (const float*)d_in[10];
    const float* w1     = (const float*)d_in[11];
    const float* b1     = (const float*)d_in[12];
    const float* w2     = (const float*)d_in[13];
    const float* b2     = (const float*)d_in[14];
    float* out = (float*)d_out;

    // ---- workspace layout ----
    char* p = (char*)d_ws;
    float*          qkv = (float*)p;
    float*          h   = (float*)p;
    unsigned short* y1  = (unsigned short*)p;
    p += (size_t)T_TOK * 2304 * 4;
    unsigned short* h_hi = (unsigned short*)p; p += (size_t)T_TOK * D_MODEL * 2;
    unsigned short* h_lo = (unsigned short*)p; p += (size_t)T_TOK * D_MODEL * 2;
    unsigned short* o_hi = h_hi;
    unsigned short* o_lo = h_lo;
    float* x1 = (float*)p; p += (size_t)T_TOK * D_MODEL * 4;
    unsigned short* Ag     = (unsigned short*)p;
    unsigned short* qwt_hi = (unsigned short*)p;
    unsigned short* qwt_lo = qwt_hi + (size_t)2304 * 768;
    p += (size_t)MPAD_MAX * D_MODEL * 2;
    unsigned short* pwt_hi = (unsigned short*)p; p += (size_t)768 * 768 * 2;
    unsigned short* pwt_lo = (unsigned short*)p; p += (size_t)768 * 768 * 2;
    unsigned short* w1t = (unsigned short*)p; p += (size_t)E_EXP * 3072 * 768 * 2;
    unsigned short* w2t = (unsigned short*)p; p += (size_t)E_EXP * 768 * 3072 * 2;
    int* routes    = (int*)p;
    int* perm      = routes + T_TOK;
    int* counts    = perm + MPAD_MAX;
    int* cursor    = counts + 8;
    int* pad_base  = cursor + 8;
    int* tile_e    = pad_base + 8;
    int* tile_row0 = tile_e + MAX_TILES;
    int* ntiles    = tile_row0 + MAX_TILES;
    // split-K fp32 partial accumulator (16-byte aligned), 15.7 MB
    char* pa = (char*)(ntiles + 1);
    pa = (char*)(((size_t)pa + 15) & ~(size_t)15);
    float* tmp = (float*)pa;

    // ---- weight preprocessing ----
    transpose_split<<<dim3(2304 / 32, 768 / 32), 256, 0, stream>>>(qkv_w, qwt_hi, qwt_lo, 768, 2304);
    transpose_split<<<dim3(768 / 32, 768 / 32), 256, 0, stream>>>(proj_w, pwt_hi, pwt_lo, 768, 768);
    transpose_bf16<<<dim3(3072 / 32, 768 / 32, 8), 256, 0, stream>>>(w1, w1t, 768, 3072);
    transpose_bf16<<<dim3(768 / 32, 3072 / 32, 8), 256, 0, stream>>>(w2, w2t, 3072, 768);

    // 1. LN1 -> split bf16 (h_hi, h_lo)
    ln_split<<<T_TOK, 256, 0, stream>>>(x, ln1_g, ln1_b, h_hi, h_lo);
    // 2. QKV (split-bf16 MFMA): qkv = h @ qkv_w   [4096 x 2304, K=768]
    sgemm<0><<<dim3(2304 / 128, T_TOK / 128), 256, 0, stream>>>(
        h_hi, h_lo, qwt_hi, qwt_lo, nullptr, nullptr, qkv, 2304, 768);
    // 3. Attention (split-bf16 MFMA flash) -> split bf16 o
    attn_mfma<<<dim3(S_SEQ / 64, H_HEADS, B_BATCH), 256, 0, stream>>>(qkv, o_hi, o_lo);
    // 4. Proj + residual (split-bf16 MFMA): x1 = x + o@proj_w + proj_b
    sgemm<1><<<dim3(768 / 128, T_TOK / 128), 256, 0, stream>>>(
        o_hi, o_lo, pwt_hi, pwt_lo, proj_b, x, x1, 768, 768);
    // 5. LN2 -> fp32 h (router path: exact fp32)
    ln_f32<<<T_TOK, 256, 0, stream>>>(x1, ln2_g, ln2_b, h);
    // 6-9. Routing (fp32, unchanged) + zero split-K accumulator
    init_kernel<<<(MPAD_MAX + 255) / 256, 256, 0, stream>>>(counts, cursor, perm);
    zero_tmp<<<(MPAD_MAX * D_MODEL / 4 + 255) / 256, 256, 0, stream>>>(tmp);
    router_kernel<<<T_TOK, 64, 0, stream>>>(h, sw, sb, routes, counts);
    moe_plan<<<1, 1, 0, stream>>>(counts, pad_base, tile_e, tile_row0, ntiles);
    scatter_kernel<<<T_TOK / 256, 256, 0, stream>>>(routes, pad_base, cursor, perm);
    // 10. Gather routed rows -> packed bf16 A
    gather_bf16<<<MPAD_MAX, 256, 0, stream>>>(h, perm, Ag);
    // 11. MoE up (bf16 MFMA): y1 = bf16(gelu(Ag @ w1t[e] + b1[e]))
    mgemm<2><<<dim3(FF_DIM / 128, MAX_TILES), 256, 0, stream>>>(
        Ag, w1t, b1, nullptr, nullptr, y1, FF_DIM, 768,
        perm, tile_e, tile_row0, ntiles);
    // 12. MoE down, split-K partials: tmp += y1 @ w2t (fp32 atomics)
    kgemm<<<dim3(D_MODEL / 128, MAX_TILES, KSPLIT), 256, 0, stream>>>(
        y1, w2t, tmp, D_MODEL, 3072, tile_e, tile_row0, ntiles);
    // 13. Epilogue: out = x1 + gelu(tmp + b2[route])
    moe_epilogue<<<MPAD_MAX, 256, 0, stream>>>(tmp, perm, routes, b2, x1, out);
}

// Round 20
// 598.302 us; speedup vs baseline: 1.1245x; 1.1245x over previous
//
#include <hip/hip_runtime.h>
#include <math.h>

// Problem constants
#define T_TOK   4096            // B*S
#define D_MODEL 768
#define H_HEADS 12
#define HDIM    64
#define S_SEQ   512
#define B_BATCH 8
#define E_EXP   8
#define FF_DIM  3072
#define MAX_TILES 40            // worst-case sum ceil(c_e/128)
#define MPAD_MAX  (MAX_TILES * 128)   // 5120

typedef __attribute__((ext_vector_type(8))) short short8;
typedef __attribute__((ext_vector_type(4))) float floatx4;

__device__ __forceinline__ float gelu_exact(float x) {
    return 0.5f * x * (1.0f + erff(x * 0.7071067811865476f));
}

// fp32 -> bf16 round-to-nearest-even
__device__ __forceinline__ unsigned short f2bf(float f) {
    unsigned int u = __float_as_uint(f);
    u += 0x7fffu + ((u >> 16) & 1u);
    return (unsigned short)(u >> 16);
}
__device__ __forceinline__ float bf2f(unsigned short h) {
    return __uint_as_float(((unsigned int)h) << 16);
}
// exact two-term bf16 split: v ~= hi + lo, |v-hi-lo| <= 2^-18 |v|
__device__ __forceinline__ void split_bf(float v, unsigned short& hi, unsigned short& lo) {
    hi = f2bf(v);
    lo = f2bf(v - bf2f(hi));
}

// async global->LDS, 16 B per lane, wave-uniform LDS base (+lane*16 implicit)
__device__ __forceinline__ void gload16(const void* g, void* l) {
    __builtin_amdgcn_global_load_lds(
        (const __attribute__((address_space(1))) unsigned int*)g,
        (__attribute__((address_space(3))) unsigned int*)l, 16, 0, 0);
}
// 16B-slot swizzle for [*][32]-short (64 B row) LDS tiles; period 16 rows.
// Staging invariant: LDS[r][s] = G[r][s ^ swz3(r)]; read XORs the same value
// back out (rule #21 both-sides-or-neither). Bank-uniform on ds_read_b128.
__device__ __forceinline__ int swz3(int r) { return (r ^ (r >> 2)) & 3; }

// ---------------- LayerNorm fp32-out ----------------
__global__ void __launch_bounds__(256) ln_f32(const float* __restrict__ x,
                                              const float* __restrict__ g,
                                              const float* __restrict__ b,
                                              float* __restrict__ out) {
    int row = blockIdx.x;
    const float* xr = x + (size_t)row * D_MODEL;
    int tid = threadIdx.x;
    float v0 = xr[tid], v1 = xr[tid + 256], v2 = xr[tid + 512];
    float s = v0 + v1 + v2;
    float q = v0 * v0 + v1 * v1 + v2 * v2;
    for (int off = 32; off; off >>= 1) {
        s += __shfl_down(s, off);
        q += __shfl_down(q, off);
    }
    __shared__ float rs[4], rq[4], stats[2];
    int wid = tid >> 6, lane = tid & 63;
    if (lane == 0) { rs[wid] = s; rq[wid] = q; }
    __syncthreads();
    if (tid == 0) {
        float ts = rs[0] + rs[1] + rs[2] + rs[3];
        float tq = rq[0] + rq[1] + rq[2] + rq[3];
        float mu = ts * (1.0f / 768.0f);
        float var = tq * (1.0f / 768.0f) - mu * mu;
        stats[0] = mu; stats[1] = rsqrtf(var + 1e-5f);
    }
    __syncthreads();
    float mu = stats[0], rstd = stats[1];
    float* orow = out + (size_t)row * D_MODEL;
    orow[tid]       = (v0 - mu) * rstd * g[tid]       + b[tid];
    orow[tid + 256] = (v1 - mu) * rstd * g[tid + 256] + b[tid + 256];
    orow[tid + 512] = (v2 - mu) * rstd * g[tid + 512] + b[tid + 512];
}

// ---------------- LayerNorm split-bf16-out ----------------
__global__ void __launch_bounds__(256) ln_split(const float* __restrict__ x,
                                                const float* __restrict__ g,
                                                const float* __restrict__ b,
                                                unsigned short* __restrict__ ohi,
                                                unsigned short* __restrict__ olo) {
    int row = blockIdx.x;
    const float* xr = x + (size_t)row * D_MODEL;
    int tid = threadIdx.x;
    float v0 = xr[tid], v1 = xr[tid + 256], v2 = xr[tid + 512];
    float s = v0 + v1 + v2;
    float q = v0 * v0 + v1 * v1 + v2 * v2;
    for (int off = 32; off; off >>= 1) {
        s += __shfl_down(s, off);
        q += __shfl_down(q, off);
    }
    __shared__ float rs[4], rq[4], stats[2];
    int wid = tid >> 6, lane = tid & 63;
    if (lane == 0) { rs[wid] = s; rq[wid] = q; }
    __syncthreads();
    if (tid == 0) {
        float ts = rs[0] + rs[1] + rs[2] + rs[3];
        float tq = rq[0] + rq[1] + rq[2] + rq[3];
        float mu = ts * (1.0f / 768.0f);
        float var = tq * (1.0f / 768.0f) - mu * mu;
        stats[0] = mu; stats[1] = rsqrtf(var + 1e-5f);
    }
    __syncthreads();
    float mu = stats[0], rstd = stats[1];
    unsigned short* hr = ohi + (size_t)row * D_MODEL;
    unsigned short* lr = olo + (size_t)row * D_MODEL;
    float r0 = (v0 - mu) * rstd * g[tid]       + b[tid];
    float r1 = (v1 - mu) * rstd * g[tid + 256] + b[tid + 256];
    float r2 = (v2 - mu) * rstd * g[tid + 512] + b[tid + 512];
    unsigned short hi, lo;
    split_bf(r0, hi, lo); hr[tid] = hi;       lr[tid] = lo;
    split_bf(r1, hi, lo); hr[tid + 256] = hi; lr[tid + 256] = lo;
    split_bf(r2, hi, lo); hr[tid + 512] = hi; lr[tid + 512] = lo;
}

// ---------------- Weight transpose fp32 -> bf16 (single) ----------------
__global__ void __launch_bounds__(256) transpose_bf16(const float* __restrict__ in,
                                                      unsigned short* __restrict__ out,
                                                      int R, int C) {
    __shared__ float t[32][33];
    const float* inb = in + (size_t)blockIdx.z * R * C;
    unsigned short* outb = out + (size_t)blockIdx.z * R * C;
    int c0 = blockIdx.x * 32, r0 = blockIdx.y * 32;
    int tx = threadIdx.x & 31, ty = threadIdx.x >> 5;
#pragma unroll
    for (int rr = 0; rr < 32; rr += 8)
        t[ty + rr][tx] = inb[(size_t)(r0 + ty + rr) * C + c0 + tx];
    __syncthreads();
#pragma unroll
    for (int rr = 0; rr < 32; rr += 8)
        outb[(size_t)(c0 + ty + rr) * R + r0 + tx] = f2bf(t[tx][ty + rr]);
}

// ---------------- Weight transpose fp32 -> split bf16 (hi+lo) -------------
__global__ void __launch_bounds__(256) transpose_split(const float* __restrict__ in,
                                                       unsigned short* __restrict__ out_hi,
                                                       unsigned short* __restrict__ out_lo,
                                                       int R, int C) {
    __shared__ float t[32][33];
    int c0 = blockIdx.x * 32, r0 = blockIdx.y * 32;
    int tx = threadIdx.x & 31, ty = threadIdx.x >> 5;
#pragma unroll
    for (int rr = 0; rr < 32; rr += 8)
        t[ty + rr][tx] = in[(size_t)(r0 + ty + rr) * C + c0 + tx];
    __syncthreads();
#pragma unroll
    for (int rr = 0; rr < 32; rr += 8) {
        float v = t[tx][ty + rr];
        unsigned short hi, lo;
        split_bf(v, hi, lo);
        size_t idx = (size_t)(c0 + ty + rr) * R + r0 + tx;
        out_hi[idx] = hi;
        out_lo[idx] = lo;
    }
}

// ---------------- MFMA flash attention (split-bf16, fp32-class accuracy) --
__global__ void __launch_bounds__(256) attn_mfma(const float* __restrict__ qkv,
                                                 unsigned short* __restrict__ ohi,
                                                 unsigned short* __restrict__ olo) {
    __shared__ __align__(16) short Kh[64][72], Kl[64][72];   // S: K ; PV: P
    __shared__ __align__(16) short Vh[64][72], Vl[64][72];   // V^T: [d][key]

    int qt = blockIdx.x, hh = blockIdx.y, bb = blockIdx.z;
    int tid = threadIdx.x;
    int lane = tid & 63, wv = tid >> 6;
    int lm = lane & 15, q8 = (lane >> 4) * 8, q4 = (lane >> 4) * 4;
    const size_t rstride = 3 * D_MODEL;
    const float* base = qkv + (size_t)bb * S_SEQ * rstride + hh * HDIM;

    // --- Q A-frags (scaled 1/8, split) directly global->registers ---
    short8 qh[2], ql[2];
    {
        const float* qrow = base + (size_t)(qt * 64 + 16 * wv + lm) * rstride;
#pragma unroll
        for (int ks = 0; ks < 2; ks++) {
            float4 v0 = *(const float4*)(qrow + ks * 32 + q8);
            float4 v1 = *(const float4*)(qrow + ks * 32 + q8 + 4);
            unsigned short h_, l_;
            short8 sh, sl;
            split_bf(v0.x * 0.125f, h_, l_); sh[0] = (short)h_; sl[0] = (short)l_;
            split_bf(v0.y * 0.125f, h_, l_); sh[1] = (short)h_; sl[1] = (short)l_;
            split_bf(v0.z * 0.125f, h_, l_); sh[2] = (short)h_; sl[2] = (short)l_;
            split_bf(v0.w * 0.125f, h_, l_); sh[3] = (short)h_; sl[3] = (short)l_;
            split_bf(v1.x * 0.125f, h_, l_); sh[4] = (short)h_; sl[4] = (short)l_;
            split_bf(v1.y * 0.125f, h_, l_); sh[5] = (short)h_; sl[5] = (short)l_;
            split_bf(v1.z * 0.125f, h_, l_); sh[6] = (short)h_; sl[6] = (short)l_;
            split_bf(v1.w * 0.125f, h_, l_); sh[7] = (short)h_; sl[7] = (short)l_;
            qh[ks] = sh; ql[ks] = sl;
        }
    }

    float m_run[4], l_run[4];
    floatx4 o_acc[4];
#pragma unroll
    for (int i = 0; i < 4; i++) {
        m_run[i] = -1e30f; l_run[i] = 0.f;
        o_acc[i] = (floatx4){0.f, 0.f, 0.f, 0.f};
    }

    int sr = tid >> 2;              // staging row 0..63
    int sc0 = (tid & 3) * 16;       // staging dim block

    for (int kt = 0; kt < 8; kt++) {
        __syncthreads();   // A: prev PV frag reads done
        {
            const float* krow = base + (size_t)(kt * 64 + sr) * rstride + D_MODEL;
            const float* vrow = krow + D_MODEL;
#pragma unroll
            for (int c = 0; c < 16; c += 4) {
                float4 kv = *(const float4*)(krow + sc0 + c);
                ushort4 h4, l4; unsigned short h_, l_;
                split_bf(kv.x, h_, l_); h4.x = h_; l4.x = l_;
                split_bf(kv.y, h_, l_); h4.y = h_; l4.y = l_;
                split_bf(kv.z, h_, l_); h4.z = h_; l4.z = l_;
                split_bf(kv.w, h_, l_); h4.w = h_; l4.w = l_;
                *(ushort4*)&Kh[sr][sc0 + c] = h4;
                *(ushort4*)&Kl[sr][sc0 + c] = l4;
                float4 vv = *(const float4*)(vrow + sc0 + c);
                split_bf(vv.x, h_, l_); Vh[sc0 + c + 0][sr] = (short)h_; Vl[sc0 + c + 0][sr] = (short)l_;
                split_bf(vv.y, h_, l_); Vh[sc0 + c + 1][sr] = (short)h_; Vl[sc0 + c + 1][sr] = (short)l_;
                split_bf(vv.z, h_, l_); Vh[sc0 + c + 2][sr] = (short)h_; Vl[sc0 + c + 2][sr] = (short)l_;
                split_bf(vv.w, h_, l_); Vh[sc0 + c + 3][sr] = (short)h_; Vl[sc0 + c + 3][sr] = (short)l_;
            }
        }
        __syncthreads();   // B: staging visible

        // S = Q @ K^T (3-term split)
        floatx4 s_acc[4];
#pragma unroll
        for (int nt = 0; nt < 4; nt++) s_acc[nt] = (floatx4){0.f, 0.f, 0.f, 0.f};
#pragma unroll
        for (int ks = 0; ks < 2; ks++) {
#pragma unroll
            for (int nt = 0; nt < 4; nt++) {
                short8 bh = *(const short8*)&Kh[nt * 16 + lm][ks * 32 + q8];
                short8 bl = *(const short8*)&Kl[nt * 16 + lm][ks * 32 + q8];
                s_acc[nt] = __builtin_amdgcn_mfma_f32_16x16x32_bf16(qh[ks], bh, s_acc[nt], 0, 0, 0);
                s_acc[nt] = __builtin_amdgcn_mfma_f32_16x16x32_bf16(qh[ks], bl, s_acc[nt], 0, 0, 0);
                s_acc[nt] = __builtin_amdgcn_mfma_f32_16x16x32_bf16(ql[ks], bh, s_acc[nt], 0, 0, 0);
            }
        }

        // Online softmax (C-layout: col=lane&15, row=q4+reg; row reduce = 16-lane quad)
        float alpha_r[4];
#pragma unroll
        for (int reg = 0; reg < 4; reg++) {
            float tm = fmaxf(fmaxf(s_acc[0][reg], s_acc[1][reg]),
                             fmaxf(s_acc[2][reg], s_acc[3][reg]));
            tm = fmaxf(tm, __shfl_xor(tm, 1));
            tm = fmaxf(tm, __shfl_xor(tm, 2));
            tm = fmaxf(tm, __shfl_xor(tm, 4));
            tm = fmaxf(tm, __shfl_xor(tm, 8));
            float mn = fmaxf(m_run[reg], tm);
            alpha_r[reg] = __expf(m_run[reg] - mn);
            m_run[reg] = mn;
            float ts = 0.f;
#pragma unroll
            for (int nt = 0; nt < 4; nt++) {
                float pv = __expf(s_acc[nt][reg] - mn);
                s_acc[nt][reg] = pv;
                ts += pv;
            }
            ts += __shfl_xor(ts, 1);
            ts += __shfl_xor(ts, 2);
            ts += __shfl_xor(ts, 4);
            ts += __shfl_xor(ts, 8);
            l_run[reg] = l_run[reg] * alpha_r[reg] + ts;
        }

        __syncthreads();   // C: all S frag reads of Kh/Kl retired -> safe to overwrite as P

        // P (split) into the K buffers: P[row][key]
#pragma unroll
        for (int nt = 0; nt < 4; nt++)
#pragma unroll
            for (int reg = 0; reg < 4; reg++) {
                unsigned short h_, l_;
                split_bf(s_acc[nt][reg], h_, l_);
                Kh[16 * wv + q4 + reg][nt * 16 + lm] = (short)h_;
                Kl[16 * wv + q4 + reg][nt * 16 + lm] = (short)l_;
            }
        // rescale O accumulator
#pragma unroll
        for (int nt = 0; nt < 4; nt++)
#pragma unroll
            for (int reg = 0; reg < 4; reg++) o_acc[nt][reg] *= alpha_r[reg];

        __syncthreads();   // D: P visible

        // O += P @ V (3-term split); A = P[m][key], B = V^T[d][key] n-major
#pragma unroll
        for (int ks = 0; ks < 2; ks++) {
            short8 ph = *(const short8*)&Kh[16 * wv + lm][ks * 32 + q8];
            short8 pl = *(const short8*)&Kl[16 * wv + lm][ks * 32 + q8];
#pragma unroll
            for (int nt = 0; nt < 4; nt++) {
                short8 vh = *(const short8*)&Vh[nt * 16 + lm][ks * 32 + q8];
                short8 vl = *(const short8*)&Vl[nt * 16 + lm][ks * 32 + q8];
                o_acc[nt] = __builtin_amdgcn_mfma_f32_16x16x32_bf16(ph, vh, o_acc[nt], 0, 0, 0);
                o_acc[nt] = __builtin_amdgcn_mfma_f32_16x16x32_bf16(ph, vl, o_acc[nt], 0, 0, 0);
                o_acc[nt] = __builtin_amdgcn_mfma_f32_16x16x32_bf16(pl, vh, o_acc[nt], 0, 0, 0);
            }
        }
    }

    // Epilogue: O/l -> split hi/lo (C-layout scatter)
    size_t ob = (size_t)(bb * S_SEQ + qt * 64) * D_MODEL + hh * HDIM;
#pragma unroll
    for (int reg = 0; reg < 4; reg++) {
        float inv = 1.0f / l_run[reg];
#pragma unroll
        for (int nt = 0; nt < 4; nt++) {
            unsigned short h_, l_;
            split_bf(o_acc[nt][reg] * inv, h_, l_);
            size_t idx = ob + (size_t)(16 * wv + q4 + reg) * D_MODEL + nt * 16 + lm;
            ohi[idx] = h_;
            olo[idx] = l_;
        }
    }
}

// ---------------- Router (fp32, exact — unchanged) -------------
__global__ void __launch_bounds__(64) router_kernel(const float* __restrict__ h2,
                                                    const float* __restrict__ sw,
                                                    const float* __restrict__ sb,
                                                    int* __restrict__ routes,
                                                    int* __restrict__ counts) {
    int t = blockIdx.x;
    int lane = threadIdx.x;
    const float* hr = h2 + (size_t)t * D_MODEL;
    float acc[8] = {};
    for (int d = lane; d < D_MODEL; d += 64) {
        float hv = hr[d];
        const float* wr = sw + (size_t)d * 8;
#pragma unroll
        for (int e = 0; e < 8; e++) acc[e] += hv * wr[e];
    }
#pragma unroll
    for (int e = 0; e < 8; e++)
        for (int off = 32; off; off >>= 1) acc[e] += __shfl_down(acc[e], off);
    if (lane == 0) {
        int best = 0;
        float bv = acc[0] + sb[0];
#pragma unroll
        for (int e = 1; e < 8; e++) {
            float v = acc[e] + sb[e];
            if (v > bv) { bv = v; best = e; }
        }
        routes[t] = best;
        atomicAdd(&counts[best], 1);
    }
}

__global__ void __launch_bounds__(256) init_kernel(int* counts, int* cursor, int* perm) {
    int idx = blockIdx.x * 256 + threadIdx.x;
    if (idx < MPAD_MAX) perm[idx] = -1;
    if (idx < 8) { counts[idx] = 0; cursor[idx] = 0; }
}

__global__ void moe_plan(const int* __restrict__ counts, int* pad_base,
                         int* tile_e, int* tile_row0, int* ntiles) {
    if (threadIdx.x == 0 && blockIdx.x == 0) {
        int base = 0, nt = 0;
        for (int e = 0; e < E_EXP; e++) {
            pad_base[e] = base;
            int c = counts[e];
            int nte = (c + 127) >> 7;
            for (int j = 0; j < nte; j++) {
                tile_e[nt] = e;
                tile_row0[nt] = base + j * 128;
                nt++;
            }
            base += nte * 128;
        }
        ntiles[0] = nt;
    }
}

__global__ void __launch_bounds__(256) scatter_kernel(const int* __restrict__ routes,
                                                      const int* __restrict__ pad_base,
                                                      int* __restrict__ cursor,
                                                      int* __restrict__ perm) {
    int t = blockIdx.x * 256 + threadIdx.x;
    if (t < T_TOK) {
        int e = routes[t];
        int pos = atomicAdd(&cursor[e], 1);
        perm[pad_base[e] + pos] = t;
    }
}

__global__ void __launch_bounds__(256) gather_bf16(const float* __restrict__ h2,
                                                   const int* __restrict__ perm,
                                                   unsigned short* __restrict__ Ag) {
    int g = blockIdx.x;
    int row = perm[g];
    unsigned short* dst = Ag + (size_t)g * D_MODEL;
    if (row >= 0) {
        const float* src = h2 + (size_t)row * D_MODEL;
        for (int d = threadIdx.x; d < D_MODEL; d += 256) dst[d] = f2bf(src[d]);
    } else {
        for (int d = threadIdx.x; d < D_MODEL; d += 256) dst[d] = 0;
    }
}

// ---------------- split-bf16 MFMA GEMM (fp32-class accuracy) ---------------
// 2-phase double-buffered pipeline: issue next K-step's global_load_lds
// BEFORE computing current step; one barrier per step.
// BK=32; LDS 2x(4x8KB)=64KB -> 2 blocks/CU cap.
// MODE 0: Cf = A@B            MODE 1: Cf = resid + A@B + bias
template <int MODE>
__global__ void __launch_bounds__(256) sgemm(const unsigned short* __restrict__ Ah_,
                                             const unsigned short* __restrict__ Al_,
                                             const unsigned short* __restrict__ Bh_,
                                             const unsigned short* __restrict__ Bl_,
                                             const float* __restrict__ bias,
                                             const float* __restrict__ resid,
                                             float* __restrict__ Cf,
                                             int N, int K) {
    __shared__ __align__(16) short Ah[2][128][32];
    __shared__ __align__(16) short Al[2][128][32];
    __shared__ __align__(16) short Bh[2][128][32];
    __shared__ __align__(16) short Bl[2][128][32];

    int row0 = blockIdx.y * 128, n0 = blockIdx.x * 128;
    int tid = threadIdx.x;
    int lane = tid & 63, wid = tid >> 6;
    int wr0 = (wid >> 1) * 64, wc0 = (wid & 1) * 64;
    int lm = lane & 15, q8 = (lane >> 4) * 8;

    int rch = lane >> 2, sl = lane & 3;
    int rst = wid * 32 + rch;
    int gsb = (sl ^ swz3(rst)) << 4;

    const unsigned short* Ahb = Ah_ + (size_t)row0 * K;
    const unsigned short* Alb = Al_ + (size_t)row0 * K;
    const unsigned short* Bhb = Bh_ + (size_t)n0 * K;
    const unsigned short* Blb = Bl_ + (size_t)n0 * K;

    const char* gAh = (const char*)(Ahb + (size_t)rst * K) + gsb;
    const char* gAl = (const char*)(Alb + (size_t)rst * K) + gsb;
    const char* gBh = (const char*)(Bhb + (size_t)rst * K) + gsb;
    const char* gBl = (const char*)(Blb + (size_t)rst * K) + gsb;
    size_t r16 = (size_t)16 * K * 2;   // +16 rows, bytes

    auto stage = [&](int b, int t) {
        size_t kb = (size_t)t * 64;    // t*32 shorts * 2B
        gload16(gAh + kb,       &Ah[b][wid * 32][0]);
        gload16(gAh + r16 + kb, &Ah[b][wid * 32 + 16][0]);
        gload16(gAl + kb,       &Al[b][wid * 32][0]);
        gload16(gAl + r16 + kb, &Al[b][wid * 32 + 16][0]);
        gload16(gBh + kb,       &Bh[b][wid * 32][0]);
        gload16(gBh + r16 + kb, &Bh[b][wid * 32 + 16][0]);
        gload16(gBl + kb,       &Bl[b][wid * 32][0]);
        gload16(gBl + r16 + kb, &Bl[b][wid * 32 + 16][0]);
    };

    floatx4 acc[4][4];
#pragma unroll
    for (int i = 0; i < 4; i++)
#pragma unroll
        for (int j = 0; j < 4; j++) acc[i][j] = (floatx4){0.f, 0.f, 0.f, 0.f};

    const int NSTEP = K >> 5;
    stage(0, 0);
    __syncthreads();   // prologue drain: buf0 ready

    int cur = 0;
    for (int t = 0; t < NSTEP; t++) {
        if (t + 1 < NSTEP) stage(cur ^ 1, t + 1);   // prefetch flies under compute

        short8 ah[4], al[4], bh[4], bl[4];
#pragma unroll
        for (int i = 0; i < 4; i++) {
            int r = wr0 + i * 16 + lm;
            int bo = (q8 * 2) ^ (swz3(r) << 4);
            ah[i] = *(const short8*)((const char*)&Ah[cur][r][0] + bo);
            al[i] = *(const short8*)((const char*)&Al[cur][r][0] + bo);
        }
#pragma unroll
        for (int j = 0; j < 4; j++) {
            int r = wc0 + j * 16 + lm;
            int bo = (q8 * 2) ^ (swz3(r) << 4);
            bh[j] = *(const short8*)((const char*)&Bh[cur][r][0] + bo);
            bl[j] = *(const short8*)((const char*)&Bl[cur][r][0] + bo);
        }
#pragma unroll
        for (int i = 0; i < 4; i++)
#pragma unroll
            for (int j = 0; j < 4; j++) {
                acc[i][j] = __builtin_amdgcn_mfma_f32_16x16x32_bf16(ah[i], bh[j], acc[i][j], 0, 0, 0);
                acc[i][j] = __builtin_amdgcn_mfma_f32_16x16x32_bf16(ah[i], bl[j], acc[i][j], 0, 0, 0);
                acc[i][j] = __builtin_amdgcn_mfma_f32_16x16x32_bf16(al[i], bh[j], acc[i][j], 0, 0, 0);
            }
        __syncthreads();   // one barrier/step
        cur ^= 1;
    }

    int q4 = (lane >> 4) * 4;
#pragma unroll
    for (int i = 0; i < 4; i++) {
#pragma unroll
        for (int j = 0; j < 4; j++) {
            int c = n0 + wc0 + j * 16 + lm;
#pragma unroll
            for (int reg = 0; reg < 4; reg++) {
                int rloc = wr0 + i * 16 + q4 + reg;
                size_t idx = (size_t)(row0 + rloc) * N + c;
                float v = acc[i][j][reg];
                if constexpr (MODE == 0) Cf[idx] = v;
                else                     Cf[idx] = resid[idx] + v + bias[c];
            }
        }
    }
}

// ---------------- bf16 MFMA GEMM (MoE up) ----------------------------------
// 2-phase double-buffered, BK=64. LDS rows are 128B: swizzle slot ^= (r&7);
// staging: linear dest + inverse-swizzled source (src slot = (l&7)^(l>>3)).
// LDS 2x2x16KB = 64KB. MODE 2: Cb = bf16(gelu(A@B + bias))
template <int MODE>
__global__ void __launch_bounds__(256) mgemm(const unsigned short* __restrict__ A,
                                             const unsigned short* __restrict__ Bt,
                                             const float* __restrict__ bias,
                                             const float* __restrict__ resid,
                                             float* __restrict__ Cf,
                                             unsigned short* __restrict__ Cb,
                                             int N, int K,
                                             const int* __restrict__ perm,
                                             const int* __restrict__ tile_e,
                                             const int* __restrict__ tile_row0,
                                             const int* __restrict__ ntiles) {
    __shared__ __align__(16) short As[2][128][64];
    __shared__ __align__(16) short Bs[2][128][64];

    if ((int)blockIdx.y >= ntiles[0]) return;
    int e = tile_e[blockIdx.y];
    int row0 = tile_row0[blockIdx.y];
    Bt += (size_t)e * N * K;
    bias += (size_t)e * N;
    int n0 = blockIdx.x * 128;

    int tid = threadIdx.x;
    int lane = tid & 63, wid = tid >> 6;
    int wr0 = (wid >> 1) * 64, wc0 = (wid & 1) * 64;
    int lm = lane & 15, q8 = (lane >> 4) * 8;

    int rl = lane >> 3, sl = lane & 7;
    int gsb = (sl ^ rl) << 4;

    const unsigned short* Abase = A + (size_t)row0 * K;
    const unsigned short* Bbase = Bt + (size_t)n0 * K;
    const char* gA = (const char*)(Abase + (size_t)(wid * 32 + rl) * K) + gsb;
    const char* gB = (const char*)(Bbase + (size_t)(wid * 32 + rl) * K) + gsb;

    auto stage = [&](int b, int t) {
        size_t kb = (size_t)t * 128;   // t*64 shorts * 2B
#pragma unroll
        for (int c = 0; c < 4; c++) {
            gload16(gA + (size_t)c * 16 * K + kb, &As[b][wid * 32 + c * 8][0]);
            gload16(gB + (size_t)c * 16 * K + kb, &Bs[b][wid * 32 + c * 8][0]);
        }
    };

    floatx4 acc[4][4];
#pragma unroll
    for (int i = 0; i < 4; i++)
#pragma unroll
        for (int j = 0; j < 4; j++) acc[i][j] = (floatx4){0.f, 0.f, 0.f, 0.f};

    const int NSTEP = K >> 6;
    stage(0, 0);
    __syncthreads();

    int cur = 0;
    for (int t = 0; t < NSTEP; t++) {
        if (t + 1 < NSTEP) stage(cur ^ 1, t + 1);

#pragma unroll
        for (int ks = 0; ks < 2; ks++) {
            short8 af[4], bfr[4];
#pragma unroll
            for (int i = 0; i < 4; i++) {
                int r = wr0 + i * 16 + lm;
                int bo = (ks * 64 + q8 * 2) ^ ((r & 7) << 4);
                af[i] = *(const short8*)((const char*)&As[cur][r][0] + bo);
            }
#pragma unroll
            for (int j = 0; j < 4; j++) {
                int r = wc0 + j * 16 + lm;
                int bo = (ks * 64 + q8 * 2) ^ ((r & 7) << 4);
                bfr[j] = *(const short8*)((const char*)&Bs[cur][r][0] + bo);
            }
#pragma unroll
            for (int i = 0; i < 4; i++)
#pragma unroll
                for (int j = 0; j < 4; j++)
                    acc[i][j] = __builtin_amdgcn_mfma_f32_16x16x32_bf16(af[i], bfr[j], acc[i][j], 0, 0, 0);
        }
        __syncthreads();
        cur ^= 1;
    }

    int q4 = (lane >> 4) * 4;
#pragma unroll
    for (int i = 0; i < 4; i++) {
#pragma unroll
        for (int j = 0; j < 4; j++) {
            int c = n0 + wc0 + j * 16 + lm;
#pragma unroll
            for (int reg = 0; reg < 4; reg++) {
                int rloc = wr0 + i * 16 + q4 + reg;
                float v = acc[i][j][reg];
                if constexpr (MODE == 2) {
                    Cb[(size_t)(row0 + rloc) * N + c] = f2bf(gelu_exact(v + bias[c]));
                } else {
                    int t = perm[row0 + rloc];
                    if (t >= 0) {
                        size_t idx = (size_t)t * N + c;
                        Cf[idx] = resid[idx] + gelu_exact(v + bias[c]);
                    }
                }
            }
        }
    }
}

// ---------------- bf16 MFMA GEMM (MoE down, BN=64 narrow tile) -------------
// Same pipeline as mgemm but BM=128 x BN=64 -> grid 12x40 = 480 blocks
// (2.3x the 128x128 tiling) to fix the measured occupancy starvation, with
// NO extra memory traffic (vs split-K's 63MB atomic RMW, R8 post-mortem).
// Waves 2Mx2N: each wave owns 64x32 (acc[4][2]). LDS 48KB -> 3 blocks/CU.
__global__ void __launch_bounds__(256) dgemm(const unsigned short* __restrict__ A,
                                             const unsigned short* __restrict__ Bt,
                                             const float* __restrict__ bias,
                                             const float* __restrict__ resid,
                                             float* __restrict__ Cf,
                                             int N, int K,
                                             const int* __restrict__ perm,
                                             const int* __restrict__ tile_e,
                                             const int* __restrict__ tile_row0,
                                             const int* __restrict__ ntiles) {
    __shared__ __align__(16) short As[2][128][64];
    __shared__ __align__(16) short Bs[2][64][64];

    if ((int)blockIdx.y >= ntiles[0]) return;
    int e = tile_e[blockIdx.y];
    int row0 = tile_row0[blockIdx.y];
    Bt += (size_t)e * N * K;
    bias += (size_t)e * N;
    int n0 = blockIdx.x * 64;

    int tid = threadIdx.x;
    int lane = tid & 63, wid = tid >> 6;
    int wr0 = (wid >> 1) * 64, wc0 = (wid & 1) * 32;
    int lm = lane & 15, q8 = (lane >> 4) * 8;

    // staging: 8-row chunks; lane row-in-chunk rl = l>>3, dest slot l&7,
    // src slot (l&7)^rl (row%8 == rl since chunks are 8-row aligned).
    int rl = lane >> 3, sl = lane & 7;
    int gsb = (sl ^ rl) << 4;

    const unsigned short* Abase = A + (size_t)row0 * K;
    const unsigned short* Bbase = Bt + (size_t)n0 * K;
    const char* gA = (const char*)(Abase + (size_t)(wid * 32 + rl) * K) + gsb;
    const char* gB = (const char*)(Bbase + (size_t)(wid * 16 + rl) * K) + gsb;

    auto stage = [&](int b, int t) {
        size_t kb = (size_t)t * 128;   // t*64 shorts * 2B
#pragma unroll
        for (int c = 0; c < 4; c++)    // A: 128 rows, wave owns 32 (4x8)
            gload16(gA + (size_t)c * 16 * K + kb, &As[b][wid * 32 + c * 8][0]);
#pragma unroll
        for (int c = 0; c < 2; c++)    // B: 64 rows, wave owns 16 (2x8)
            gload16(gB + (size_t)c * 16 * K + kb, &Bs[b][wid * 16 + c * 8][0]);
    };

    floatx4 acc[4][2];
#pragma unroll
    for (int i = 0; i < 4; i++)
#pragma unroll
        for (int j = 0; j < 2; j++) acc[i][j] = (floatx4){0.f, 0.f, 0.f, 0.f};

    const int NSTEP = K >> 6;          // 48
    stage(0, 0);
    __syncthreads();

    int cur = 0;
    for (int t = 0; t < NSTEP; t++) {
        if (t + 1 < NSTEP) stage(cur ^ 1, t + 1);

#pragma unroll
        for (int ks = 0; ks < 2; ks++) {
            short8 af[4], bfr[2];
#pragma unroll
            for (int i = 0; i < 4; i++) {
                int r = wr0 + i * 16 + lm;
                int bo = (ks * 64 + q8 * 2) ^ ((r & 7) << 4);
                af[i] = *(const short8*)((const char*)&As[cur][r][0] + bo);
            }
#pragma unroll
            for (int j = 0; j < 2; j++) {
                int r = wc0 + j * 16 + lm;
                int bo = (ks * 64 + q8 * 2) ^ ((r & 7) << 4);
                bfr[j] = *(const short8*)((const char*)&Bs[cur][r][0] + bo);
            }
#pragma unroll
            for (int i = 0; i < 4; i++)
#pragma unroll
                for (int j = 0; j < 2; j++)
                    acc[i][j] = __builtin_amdgcn_mfma_f32_16x16x32_bf16(af[i], bfr[j], acc[i][j], 0, 0, 0);
        }
        __syncthreads();
        cur ^= 1;
    }

    int q4 = (lane >> 4) * 4;
#pragma unroll
    for (int i = 0; i < 4; i++) {
#pragma unroll
        for (int j = 0; j < 2; j++) {
            int c = n0 + wc0 + j * 16 + lm;
#pragma unroll
            for (int reg = 0; reg < 4; reg++) {
                int rloc = wr0 + i * 16 + q4 + reg;
                int t = perm[row0 + rloc];
                if (t >= 0) {
                    size_t idx = (size_t)t * N + c;
                    Cf[idx] = resid[idx] + gelu_exact(acc[i][j][reg] + bias[c]);
                }
            }
        }
    }
}

extern "C" void kernel_launch(void* const* d_in, const int* in_sizes, int n_in,
                              void* d_out, int out_size, void* d_ws, size_t ws_size,
                              hipStream_t stream) {
    const float* x      = (const float*)d_in[0];
    const float* ln1_g  = (const float*)d_in[2];
    const float* ln1_b  = (const float*)d_in[3];
    const float* qkv_w  = (const float*)d_in[4];
    const float* proj_w = (const float*)d_in[5];
    const float* proj_b = (const float*)d_in[6];
    const float* ln2_g  = (const float*)d_in[7];
    const float* ln2_b  = (const float*)d_in[8];
    const float* sw     = (const float*)d_in[9];
    const float* sb     = (const float*)d_in[10];
    const float* w1     = (const float*)d_in[11];
    const float* b1     = (const float*)d_in[12];
    const float* w2     = (const float*)d_in[13];
    const float* b2     = (const float*)d_in[14];
    float* out = (float*)d_out;

    // ---- workspace layout ----
    char* p = (char*)d_ws;
    float*          qkv = (float*)p;
    float*          h   = (float*)p;
    unsigned short* y1  = (unsigned short*)p;
    p += (size_t)T_TOK * 2304 * 4;
    unsigned short* h_hi = (unsigned short*)p; p += (size_t)T_TOK * D_MODEL * 2;
    unsigned short* h_lo = (unsigned short*)p; p += (size_t)T_TOK * D_MODEL * 2;
    unsigned short* o_hi = h_hi;
    unsigned short* o_lo = h_lo;
    float* x1 = (float*)p; p += (size_t)T_TOK * D_MODEL * 4;
    unsigned short* Ag     = (unsigned short*)p;
    unsigned short* qwt_hi = (unsigned short*)p;
    unsigned short* qwt_lo = qwt_hi + (size_t)2304 * 768;
    p += (size_t)MPAD_MAX * D_MODEL * 2;
    unsigned short* pwt_hi = (unsigned short*)p; p += (size_t)768 * 768 * 2;
    unsigned short* pwt_lo = (unsigned short*)p; p += (size_t)768 * 768 * 2;
    unsigned short* w1t = (unsigned short*)p; p += (size_t)E_EXP * 3072 * 768 * 2;
    unsigned short* w2t = (unsigned short*)p; p += (size_t)E_EXP * 768 * 3072 * 2;
    int* routes    = (int*)p;
    int* perm      = routes + T_TOK;
    int* counts    = perm + MPAD_MAX;
    int* cursor    = counts + 8;
    int* pad_base  = cursor + 8;
    int* tile_e    = pad_base + 8;
    int* tile_row0 = tile_e + MAX_TILES;
    int* ntiles    = tile_row0 + MAX_TILES;

    // ---- weight preprocessing ----
    transpose_split<<<dim3(2304 / 32, 768 / 32), 256, 0, stream>>>(qkv_w, qwt_hi, qwt_lo, 768, 2304);
    transpose_split<<<dim3(768 / 32, 768 / 32), 256, 0, stream>>>(proj_w, pwt_hi, pwt_lo, 768, 768);
    transpose_bf16<<<dim3(3072 / 32, 768 / 32, 8), 256, 0, stream>>>(w1, w1t, 768, 3072);
    transpose_bf16<<<dim3(768 / 32, 3072 / 32, 8), 256, 0, stream>>>(w2, w2t, 3072, 768);

    // 1. LN1 -> split bf16 (h_hi, h_lo)
    ln_split<<<T_TOK, 256, 0, stream>>>(x, ln1_g, ln1_b, h_hi, h_lo);
    // 2. QKV (split-bf16 MFMA): qkv = h @ qkv_w   [4096 x 2304, K=768]
    sgemm<0><<<dim3(2304 / 128, T_TOK / 128), 256, 0, stream>>>(
        h_hi, h_lo, qwt_hi, qwt_lo, nullptr, nullptr, qkv, 2304, 768);
    // 3. Attention (split-bf16 MFMA flash) -> split bf16 o
    attn_mfma<<<dim3(S_SEQ / 64, H_HEADS, B_BATCH), 256, 0, stream>>>(qkv, o_hi, o_lo);
    // 4. Proj + residual (split-bf16 MFMA): x1 = x + o@proj_w + proj_b
    sgemm<1><<<dim3(768 / 128, T_TOK / 128), 256, 0, stream>>>(
        o_hi, o_lo, pwt_hi, pwt_lo, proj_b, x, x1, 768, 768);
    // 5. LN2 -> fp32 h (router path: exact fp32)
    ln_f32<<<T_TOK, 256, 0, stream>>>(x1, ln2_g, ln2_b, h);
    // 6-9. Routing (fp32, unchanged)
    init_kernel<<<(MPAD_MAX + 255) / 256, 256, 0, stream>>>(counts, cursor, perm);
    router_kernel<<<T_TOK, 64, 0, stream>>>(h, sw, sb, routes, counts);
    moe_plan<<<1, 1, 0, stream>>>(counts, pad_base, tile_e, tile_row0, ntiles);
    scatter_kernel<<<T_TOK / 256, 256, 0, stream>>>(routes, pad_base, cursor, perm);
    // 10. Gather routed rows -> packed bf16 A
    gather_bf16<<<MPAD_MAX, 256, 0, stream>>>(h, perm, Ag);
    // 11. MoE up (bf16 MFMA): y1 = bf16(gelu(Ag @ w1t[e] + b1[e]))
    mgemm<2><<<dim3(FF_DIM / 128, MAX_TILES), 256, 0, stream>>>(
        Ag, w1t, b1, nullptr, nullptr, y1, FF_DIM, 768,
        perm, tile_e, tile_row0, ntiles);
    // 12. MoE down + residual scatter, BN=64 tile: 480 blocks
    dgemm<<<dim3(D_MODEL / 64, MAX_TILES), 256, 0, stream>>>(
        y1, w2t, b2, x1, out, D_MODEL, 3072,
        perm, tile_e, tile_row0, ntiles);
}

// Round 21
// 578.729 us; speedup vs baseline: 1.1625x; 1.0338x over previous
//
#include <hip/hip_runtime.h>
#include <math.h>

// Problem constants
#define T_TOK   4096            // B*S
#define D_MODEL 768
#define H_HEADS 12
#define HDIM    64
#define S_SEQ   512
#define B_BATCH 8
#define E_EXP   8
#define FF_DIM  3072
#define MAX_TILES 40            // worst-case sum ceil(c_e/128)
#define MPAD_MAX  (MAX_TILES * 128)   // 5120

typedef __attribute__((ext_vector_type(8))) short short8;
typedef __attribute__((ext_vector_type(4))) float floatx4;

__device__ __forceinline__ float gelu_exact(float x) {
    return 0.5f * x * (1.0f + erff(x * 0.7071067811865476f));
}

// fp32 -> bf16 round-to-nearest-even
__device__ __forceinline__ unsigned short f2bf(float f) {
    unsigned int u = __float_as_uint(f);
    u += 0x7fffu + ((u >> 16) & 1u);
    return (unsigned short)(u >> 16);
}
__device__ __forceinline__ float bf2f(unsigned short h) {
    return __uint_as_float(((unsigned int)h) << 16);
}
// exact two-term bf16 split: v ~= hi + lo, |v-hi-lo| <= 2^-18 |v|
__device__ __forceinline__ void split_bf(float v, unsigned short& hi, unsigned short& lo) {
    hi = f2bf(v);
    lo = f2bf(v - bf2f(hi));
}

// async global->LDS, 16 B per lane, wave-uniform LDS base (+lane*16 implicit)
__device__ __forceinline__ void gload16(const void* g, void* l) {
    __builtin_amdgcn_global_load_lds(
        (const __attribute__((address_space(1))) unsigned int*)g,
        (__attribute__((address_space(3))) unsigned int*)l, 16, 0, 0);
}
// 16B-slot swizzle for [*][32]-short (64 B row) LDS tiles; period 16 rows.
// Staging invariant: LDS[r][s] = G[r][s ^ swz3(r)]; read XORs the same value
// back out (rule #21 both-sides-or-neither). Bank-uniform on ds_read_b128.
__device__ __forceinline__ int swz3(int r) { return (r ^ (r >> 2)) & 3; }

// ---------------- LayerNorm fp32-out ----------------
__global__ void __launch_bounds__(256) ln_f32(const float* __restrict__ x,
                                              const float* __restrict__ g,
                                              const float* __restrict__ b,
                                              float* __restrict__ out) {
    int row = blockIdx.x;
    const float* xr = x + (size_t)row * D_MODEL;
    int tid = threadIdx.x;
    float v0 = xr[tid], v1 = xr[tid + 256], v2 = xr[tid + 512];
    float s = v0 + v1 + v2;
    float q = v0 * v0 + v1 * v1 + v2 * v2;
    for (int off = 32; off; off >>= 1) {
        s += __shfl_down(s, off);
        q += __shfl_down(q, off);
    }
    __shared__ float rs[4], rq[4], stats[2];
    int wid = tid >> 6, lane = tid & 63;
    if (lane == 0) { rs[wid] = s; rq[wid] = q; }
    __syncthreads();
    if (tid == 0) {
        float ts = rs[0] + rs[1] + rs[2] + rs[3];
        float tq = rq[0] + rq[1] + rq[2] + rq[3];
        float mu = ts * (1.0f / 768.0f);
        float var = tq * (1.0f / 768.0f) - mu * mu;
        stats[0] = mu; stats[1] = rsqrtf(var + 1e-5f);
    }
    __syncthreads();
    float mu = stats[0], rstd = stats[1];
    float* orow = out + (size_t)row * D_MODEL;
    orow[tid]       = (v0 - mu) * rstd * g[tid]       + b[tid];
    orow[tid + 256] = (v1 - mu) * rstd * g[tid + 256] + b[tid + 256];
    orow[tid + 512] = (v2 - mu) * rstd * g[tid + 512] + b[tid + 512];
}

// ---------------- LayerNorm split-bf16-out ----------------
__global__ void __launch_bounds__(256) ln_split(const float* __restrict__ x,
                                                const float* __restrict__ g,
                                                const float* __restrict__ b,
                                                unsigned short* __restrict__ ohi,
                                                unsigned short* __restrict__ olo) {
    int row = blockIdx.x;
    const float* xr = x + (size_t)row * D_MODEL;
    int tid = threadIdx.x;
    float v0 = xr[tid], v1 = xr[tid + 256], v2 = xr[tid + 512];
    float s = v0 + v1 + v2;
    float q = v0 * v0 + v1 * v1 + v2 * v2;
    for (int off = 32; off; off >>= 1) {
        s += __shfl_down(s, off);
        q += __shfl_down(q, off);
    }
    __shared__ float rs[4], rq[4], stats[2];
    int wid = tid >> 6, lane = tid & 63;
    if (lane == 0) { rs[wid] = s; rq[wid] = q; }
    __syncthreads();
    if (tid == 0) {
        float ts = rs[0] + rs[1] + rs[2] + rs[3];
        float tq = rq[0] + rq[1] + rq[2] + rq[3];
        float mu = ts * (1.0f / 768.0f);
        float var = tq * (1.0f / 768.0f) - mu * mu;
        stats[0] = mu; stats[1] = rsqrtf(var + 1e-5f);
    }
    __syncthreads();
    float mu = stats[0], rstd = stats[1];
    unsigned short* hr = ohi + (size_t)row * D_MODEL;
    unsigned short* lr = olo + (size_t)row * D_MODEL;
    float r0 = (v0 - mu) * rstd * g[tid]       + b[tid];
    float r1 = (v1 - mu) * rstd * g[tid + 256] + b[tid + 256];
    float r2 = (v2 - mu) * rstd * g[tid + 512] + b[tid + 512];
    unsigned short hi, lo;
    split_bf(r0, hi, lo); hr[tid] = hi;       lr[tid] = lo;
    split_bf(r1, hi, lo); hr[tid + 256] = hi; lr[tid + 256] = lo;
    split_bf(r2, hi, lo); hr[tid + 512] = hi; lr[tid + 512] = lo;
}

// ---------------- Weight transpose fp32 -> bf16 (single) ----------------
__global__ void __launch_bounds__(256) transpose_bf16(const float* __restrict__ in,
                                                      unsigned short* __restrict__ out,
                                                      int R, int C) {
    __shared__ float t[32][33];
    const float* inb = in + (size_t)blockIdx.z * R * C;
    unsigned short* outb = out + (size_t)blockIdx.z * R * C;
    int c0 = blockIdx.x * 32, r0 = blockIdx.y * 32;
    int tx = threadIdx.x & 31, ty = threadIdx.x >> 5;
#pragma unroll
    for (int rr = 0; rr < 32; rr += 8)
        t[ty + rr][tx] = inb[(size_t)(r0 + ty + rr) * C + c0 + tx];
    __syncthreads();
#pragma unroll
    for (int rr = 0; rr < 32; rr += 8)
        outb[(size_t)(c0 + ty + rr) * R + r0 + tx] = f2bf(t[tx][ty + rr]);
}

// ---------------- Weight transpose fp32 -> split bf16 (hi+lo) -------------
__global__ void __launch_bounds__(256) transpose_split(const float* __restrict__ in,
                                                       unsigned short* __restrict__ out_hi,
                                                       unsigned short* __restrict__ out_lo,
                                                       int R, int C) {
    __shared__ float t[32][33];
    int c0 = blockIdx.x * 32, r0 = blockIdx.y * 32;
    int tx = threadIdx.x & 31, ty = threadIdx.x >> 5;
#pragma unroll
    for (int rr = 0; rr < 32; rr += 8)
        t[ty + rr][tx] = in[(size_t)(r0 + ty + rr) * C + c0 + tx];
    __syncthreads();
#pragma unroll
    for (int rr = 0; rr < 32; rr += 8) {
        float v = t[tx][ty + rr];
        unsigned short hi, lo;
        split_bf(v, hi, lo);
        size_t idx = (size_t)(c0 + ty + rr) * R + r0 + tx;
        out_hi[idx] = hi;
        out_lo[idx] = lo;
    }
}

// ---------------- MFMA flash attention (split-bf16, fp32-class accuracy) --
__global__ void __launch_bounds__(256) attn_mfma(const float* __restrict__ qkv,
                                                 unsigned short* __restrict__ ohi,
                                                 unsigned short* __restrict__ olo) {
    __shared__ __align__(16) short Kh[64][72], Kl[64][72];   // S: K ; PV: P
    __shared__ __align__(16) short Vh[64][72], Vl[64][72];   // V^T: [d][key]

    int qt = blockIdx.x, hh = blockIdx.y, bb = blockIdx.z;
    int tid = threadIdx.x;
    int lane = tid & 63, wv = tid >> 6;
    int lm = lane & 15, q8 = (lane >> 4) * 8, q4 = (lane >> 4) * 4;
    const size_t rstride = 3 * D_MODEL;
    const float* base = qkv + (size_t)bb * S_SEQ * rstride + hh * HDIM;

    // --- Q A-frags (scaled 1/8, split) directly global->registers ---
    short8 qh[2], ql[2];
    {
        const float* qrow = base + (size_t)(qt * 64 + 16 * wv + lm) * rstride;
#pragma unroll
        for (int ks = 0; ks < 2; ks++) {
            float4 v0 = *(const float4*)(qrow + ks * 32 + q8);
            float4 v1 = *(const float4*)(qrow + ks * 32 + q8 + 4);
            unsigned short h_, l_;
            short8 sh, sl;
            split_bf(v0.x * 0.125f, h_, l_); sh[0] = (short)h_; sl[0] = (short)l_;
            split_bf(v0.y * 0.125f, h_, l_); sh[1] = (short)h_; sl[1] = (short)l_;
            split_bf(v0.z * 0.125f, h_, l_); sh[2] = (short)h_; sl[2] = (short)l_;
            split_bf(v0.w * 0.125f, h_, l_); sh[3] = (short)h_; sl[3] = (short)l_;
            split_bf(v1.x * 0.125f, h_, l_); sh[4] = (short)h_; sl[4] = (short)l_;
            split_bf(v1.y * 0.125f, h_, l_); sh[5] = (short)h_; sl[5] = (short)l_;
            split_bf(v1.z * 0.125f, h_, l_); sh[6] = (short)h_; sl[6] = (short)l_;
            split_bf(v1.w * 0.125f, h_, l_); sh[7] = (short)h_; sl[7] = (short)l_;
            qh[ks] = sh; ql[ks] = sl;
        }
    }

    float m_run[4], l_run[4];
    floatx4 o_acc[4];
#pragma unroll
    for (int i = 0; i < 4; i++) {
        m_run[i] = -1e30f; l_run[i] = 0.f;
        o_acc[i] = (floatx4){0.f, 0.f, 0.f, 0.f};
    }

    int sr = tid >> 2;              // staging row 0..63
    int sc0 = (tid & 3) * 16;       // staging dim block

    for (int kt = 0; kt < 8; kt++) {
        __syncthreads();   // A: prev PV frag reads done
        {
            const float* krow = base + (size_t)(kt * 64 + sr) * rstride + D_MODEL;
            const float* vrow = krow + D_MODEL;
#pragma unroll
            for (int c = 0; c < 16; c += 4) {
                float4 kv = *(const float4*)(krow + sc0 + c);
                ushort4 h4, l4; unsigned short h_, l_;
                split_bf(kv.x, h_, l_); h4.x = h_; l4.x = l_;
                split_bf(kv.y, h_, l_); h4.y = h_; l4.y = l_;
                split_bf(kv.z, h_, l_); h4.z = h_; l4.z = l_;
                split_bf(kv.w, h_, l_); h4.w = h_; l4.w = l_;
                *(ushort4*)&Kh[sr][sc0 + c] = h4;
                *(ushort4*)&Kl[sr][sc0 + c] = l4;
                float4 vv = *(const float4*)(vrow + sc0 + c);
                split_bf(vv.x, h_, l_); Vh[sc0 + c + 0][sr] = (short)h_; Vl[sc0 + c + 0][sr] = (short)l_;
                split_bf(vv.y, h_, l_); Vh[sc0 + c + 1][sr] = (short)h_; Vl[sc0 + c + 1][sr] = (short)l_;
                split_bf(vv.z, h_, l_); Vh[sc0 + c + 2][sr] = (short)h_; Vl[sc0 + c + 2][sr] = (short)l_;
                split_bf(vv.w, h_, l_); Vh[sc0 + c + 3][sr] = (short)h_; Vl[sc0 + c + 3][sr] = (short)l_;
            }
        }
        __syncthreads();   // B: staging visible

        // S = Q @ K^T (3-term split)
        floatx4 s_acc[4];
#pragma unroll
        for (int nt = 0; nt < 4; nt++) s_acc[nt] = (floatx4){0.f, 0.f, 0.f, 0.f};
#pragma unroll
        for (int ks = 0; ks < 2; ks++) {
#pragma unroll
            for (int nt = 0; nt < 4; nt++) {
                short8 bh = *(const short8*)&Kh[nt * 16 + lm][ks * 32 + q8];
                short8 bl = *(const short8*)&Kl[nt * 16 + lm][ks * 32 + q8];
                s_acc[nt] = __builtin_amdgcn_mfma_f32_16x16x32_bf16(qh[ks], bh, s_acc[nt], 0, 0, 0);
                s_acc[nt] = __builtin_amdgcn_mfma_f32_16x16x32_bf16(qh[ks], bl, s_acc[nt], 0, 0, 0);
                s_acc[nt] = __builtin_amdgcn_mfma_f32_16x16x32_bf16(ql[ks], bh, s_acc[nt], 0, 0, 0);
            }
        }

        // Online softmax (C-layout: col=lane&15, row=q4+reg; row reduce = 16-lane quad)
        float alpha_r[4];
#pragma unroll
        for (int reg = 0; reg < 4; reg++) {
            float tm = fmaxf(fmaxf(s_acc[0][reg], s_acc[1][reg]),
                             fmaxf(s_acc[2][reg], s_acc[3][reg]));
            tm = fmaxf(tm, __shfl_xor(tm, 1));
            tm = fmaxf(tm, __shfl_xor(tm, 2));
            tm = fmaxf(tm, __shfl_xor(tm, 4));
            tm = fmaxf(tm, __shfl_xor(tm, 8));
            float mn = fmaxf(m_run[reg], tm);
            alpha_r[reg] = __expf(m_run[reg] - mn);
            m_run[reg] = mn;
            float ts = 0.f;
#pragma unroll
            for (int nt = 0; nt < 4; nt++) {
                float pv = __expf(s_acc[nt][reg] - mn);
                s_acc[nt][reg] = pv;
                ts += pv;
            }
            ts += __shfl_xor(ts, 1);
            ts += __shfl_xor(ts, 2);
            ts += __shfl_xor(ts, 4);
            ts += __shfl_xor(ts, 8);
            l_run[reg] = l_run[reg] * alpha_r[reg] + ts;
        }

        __syncthreads();   // C: all S frag reads of Kh/Kl retired -> safe to overwrite as P

        // P (split) into the K buffers: P[row][key]
#pragma unroll
        for (int nt = 0; nt < 4; nt++)
#pragma unroll
            for (int reg = 0; reg < 4; reg++) {
                unsigned short h_, l_;
                split_bf(s_acc[nt][reg], h_, l_);
                Kh[16 * wv + q4 + reg][nt * 16 + lm] = (short)h_;
                Kl[16 * wv + q4 + reg][nt * 16 + lm] = (short)l_;
            }
        // rescale O accumulator
#pragma unroll
        for (int nt = 0; nt < 4; nt++)
#pragma unroll
            for (int reg = 0; reg < 4; reg++) o_acc[nt][reg] *= alpha_r[reg];

        __syncthreads();   // D: P visible

        // O += P @ V (3-term split); A = P[m][key], B = V^T[d][key] n-major
#pragma unroll
        for (int ks = 0; ks < 2; ks++) {
            short8 ph = *(const short8*)&Kh[16 * wv + lm][ks * 32 + q8];
            short8 pl = *(const short8*)&Kl[16 * wv + lm][ks * 32 + q8];
#pragma unroll
            for (int nt = 0; nt < 4; nt++) {
                short8 vh = *(const short8*)&Vh[nt * 16 + lm][ks * 32 + q8];
                short8 vl = *(const short8*)&Vl[nt * 16 + lm][ks * 32 + q8];
                o_acc[nt] = __builtin_amdgcn_mfma_f32_16x16x32_bf16(ph, vh, o_acc[nt], 0, 0, 0);
                o_acc[nt] = __builtin_amdgcn_mfma_f32_16x16x32_bf16(ph, vl, o_acc[nt], 0, 0, 0);
                o_acc[nt] = __builtin_amdgcn_mfma_f32_16x16x32_bf16(pl, vh, o_acc[nt], 0, 0, 0);
            }
        }
    }

    // Epilogue: O/l -> split hi/lo (C-layout scatter)
    size_t ob = (size_t)(bb * S_SEQ + qt * 64) * D_MODEL + hh * HDIM;
#pragma unroll
    for (int reg = 0; reg < 4; reg++) {
        float inv = 1.0f / l_run[reg];
#pragma unroll
        for (int nt = 0; nt < 4; nt++) {
            unsigned short h_, l_;
            split_bf(o_acc[nt][reg] * inv, h_, l_);
            size_t idx = ob + (size_t)(16 * wv + q4 + reg) * D_MODEL + nt * 16 + lm;
            ohi[idx] = h_;
            olo[idx] = l_;
        }
    }
}

// ---------------- Router (fp32, exact — unchanged) -------------
__global__ void __launch_bounds__(64) router_kernel(const float* __restrict__ h2,
                                                    const float* __restrict__ sw,
                                                    const float* __restrict__ sb,
                                                    int* __restrict__ routes,
                                                    int* __restrict__ counts) {
    int t = blockIdx.x;
    int lane = threadIdx.x;
    const float* hr = h2 + (size_t)t * D_MODEL;
    float acc[8] = {};
    for (int d = lane; d < D_MODEL; d += 64) {
        float hv = hr[d];
        const float* wr = sw + (size_t)d * 8;
#pragma unroll
        for (int e = 0; e < 8; e++) acc[e] += hv * wr[e];
    }
#pragma unroll
    for (int e = 0; e < 8; e++)
        for (int off = 32; off; off >>= 1) acc[e] += __shfl_down(acc[e], off);
    if (lane == 0) {
        int best = 0;
        float bv = acc[0] + sb[0];
#pragma unroll
        for (int e = 1; e < 8; e++) {
            float v = acc[e] + sb[e];
            if (v > bv) { bv = v; best = e; }
        }
        routes[t] = best;
        atomicAdd(&counts[best], 1);
    }
}

__global__ void __launch_bounds__(256) init_kernel(int* counts, int* cursor, int* perm) {
    int idx = blockIdx.x * 256 + threadIdx.x;
    if (idx < MPAD_MAX) perm[idx] = -1;
    if (idx < 8) { counts[idx] = 0; cursor[idx] = 0; }
}

__global__ void moe_plan(const int* __restrict__ counts, int* pad_base,
                         int* tile_e, int* tile_row0, int* ntiles) {
    if (threadIdx.x == 0 && blockIdx.x == 0) {
        int base = 0, nt = 0;
        for (int e = 0; e < E_EXP; e++) {
            pad_base[e] = base;
            int c = counts[e];
            int nte = (c + 127) >> 7;
            for (int j = 0; j < nte; j++) {
                tile_e[nt] = e;
                tile_row0[nt] = base + j * 128;
                nt++;
            }
            base += nte * 128;
        }
        ntiles[0] = nt;
    }
}

__global__ void __launch_bounds__(256) scatter_kernel(const int* __restrict__ routes,
                                                      const int* __restrict__ pad_base,
                                                      int* __restrict__ cursor,
                                                      int* __restrict__ perm) {
    int t = blockIdx.x * 256 + threadIdx.x;
    if (t < T_TOK) {
        int e = routes[t];
        int pos = atomicAdd(&cursor[e], 1);
        perm[pad_base[e] + pos] = t;
    }
}

__global__ void __launch_bounds__(256) gather_bf16(const float* __restrict__ h2,
                                                   const int* __restrict__ perm,
                                                   unsigned short* __restrict__ Ag) {
    int g = blockIdx.x;
    int row = perm[g];
    unsigned short* dst = Ag + (size_t)g * D_MODEL;
    if (row >= 0) {
        const float* src = h2 + (size_t)row * D_MODEL;
        for (int d = threadIdx.x; d < D_MODEL; d += 256) dst[d] = f2bf(src[d]);
    } else {
        for (int d = threadIdx.x; d < D_MODEL; d += 256) dst[d] = 0;
    }
}

// ---------------- split-bf16 MFMA GEMM (fp32-class accuracy) ---------------
// NARROW TILE: BM=128 x BN=64, BK=32, 2-phase double-buffered pipeline.
// R20 counters: old BN=128 version was occupancy-capped (12.6%, 64KB LDS ->
// 2 blk/CU; QKV grid 576=2.25x256 tail; proj grid 192 starved). BN=64:
// LDS 48KB -> 3 blk/CU; QKV grid 1152 (4.5/CU), proj 384. Waves 2Mx2N, each
// 64x32 (acc[4][2]). Same both-sides swz3 staging invariant.
// MODE 0: Cf = A@B            MODE 1: Cf = resid + A@B + bias
template <int MODE>
__global__ void __launch_bounds__(256) sgemm(const unsigned short* __restrict__ Ah_,
                                             const unsigned short* __restrict__ Al_,
                                             const unsigned short* __restrict__ Bh_,
                                             const unsigned short* __restrict__ Bl_,
                                             const float* __restrict__ bias,
                                             const float* __restrict__ resid,
                                             float* __restrict__ Cf,
                                             int N, int K) {
    __shared__ __align__(16) short Ah[2][128][32];
    __shared__ __align__(16) short Al[2][128][32];
    __shared__ __align__(16) short Bh[2][64][32];
    __shared__ __align__(16) short Bl[2][64][32];

    int row0 = blockIdx.y * 128, n0 = blockIdx.x * 64;
    int tid = threadIdx.x;
    int lane = tid & 63, wid = tid >> 6;
    int wr0 = (wid >> 1) * 64, wc0 = (wid & 1) * 32;
    int lm = lane & 15, q8 = (lane >> 4) * 8;

    // A staging: wave owns rows [32*wid, +32), 2 chunks of 16 rows.
    // Lane: row = chunk*16 + (lane>>2), dest slot lane&3, src slot ^swz3(row).
    int rch = lane >> 2, sl = lane & 3;
    int rstA = wid * 32 + rch;
    int gsbA = (sl ^ swz3(rstA)) << 4;   // swz3 period 16 -> same for chunk 1
    // B staging: wave owns rows [16*wid, +16), 1 chunk of 16 rows.
    int rstB = wid * 16 + rch;
    int gsbB = (sl ^ swz3(rstB)) << 4;

    const unsigned short* Ahb = Ah_ + (size_t)row0 * K;
    const unsigned short* Alb = Al_ + (size_t)row0 * K;
    const unsigned short* Bhb = Bh_ + (size_t)n0 * K;
    const unsigned short* Blb = Bl_ + (size_t)n0 * K;

    const char* gAh = (const char*)(Ahb + (size_t)rstA * K) + gsbA;
    const char* gAl = (const char*)(Alb + (size_t)rstA * K) + gsbA;
    const char* gBh = (const char*)(Bhb + (size_t)rstB * K) + gsbB;
    const char* gBl = (const char*)(Blb + (size_t)rstB * K) + gsbB;
    size_t r16 = (size_t)16 * K * 2;   // +16 rows, bytes

    auto stage = [&](int b, int t) {
        size_t kb = (size_t)t * 64;    // t*32 shorts * 2B
        gload16(gAh + kb,       &Ah[b][wid * 32][0]);
        gload16(gAh + r16 + kb, &Ah[b][wid * 32 + 16][0]);
        gload16(gAl + kb,       &Al[b][wid * 32][0]);
        gload16(gAl + r16 + kb, &Al[b][wid * 32 + 16][0]);
        gload16(gBh + kb,       &Bh[b][wid * 16][0]);
        gload16(gBl + kb,       &Bl[b][wid * 16][0]);
    };

    floatx4 acc[4][2];
#pragma unroll
    for (int i = 0; i < 4; i++)
#pragma unroll
        for (int j = 0; j < 2; j++) acc[i][j] = (floatx4){0.f, 0.f, 0.f, 0.f};

    const int NSTEP = K >> 5;
    stage(0, 0);
    __syncthreads();   // prologue drain: buf0 ready

    int cur = 0;
    for (int t = 0; t < NSTEP; t++) {
        if (t + 1 < NSTEP) stage(cur ^ 1, t + 1);   // prefetch flies under compute

        short8 ah[4], al[4], bh[2], bl[2];
#pragma unroll
        for (int i = 0; i < 4; i++) {
            int r = wr0 + i * 16 + lm;
            int bo = (q8 * 2) ^ (swz3(r) << 4);
            ah[i] = *(const short8*)((const char*)&Ah[cur][r][0] + bo);
            al[i] = *(const short8*)((const char*)&Al[cur][r][0] + bo);
        }
#pragma unroll
        for (int j = 0; j < 2; j++) {
            int r = wc0 + j * 16 + lm;
            int bo = (q8 * 2) ^ (swz3(r) << 4);
            bh[j] = *(const short8*)((const char*)&Bh[cur][r][0] + bo);
            bl[j] = *(const short8*)((const char*)&Bl[cur][r][0] + bo);
        }
#pragma unroll
        for (int i = 0; i < 4; i++)
#pragma unroll
            for (int j = 0; j < 2; j++) {
                acc[i][j] = __builtin_amdgcn_mfma_f32_16x16x32_bf16(ah[i], bh[j], acc[i][j], 0, 0, 0);
                acc[i][j] = __builtin_amdgcn_mfma_f32_16x16x32_bf16(ah[i], bl[j], acc[i][j], 0, 0, 0);
                acc[i][j] = __builtin_amdgcn_mfma_f32_16x16x32_bf16(al[i], bh[j], acc[i][j], 0, 0, 0);
            }
        __syncthreads();   // one barrier/step
        cur ^= 1;
    }

    int q4 = (lane >> 4) * 4;
#pragma unroll
    for (int i = 0; i < 4; i++) {
#pragma unroll
        for (int j = 0; j < 2; j++) {
            int c = n0 + wc0 + j * 16 + lm;
#pragma unroll
            for (int reg = 0; reg < 4; reg++) {
                int rloc = wr0 + i * 16 + q4 + reg;
                size_t idx = (size_t)(row0 + rloc) * N + c;
                float v = acc[i][j][reg];
                if constexpr (MODE == 0) Cf[idx] = v;
                else                     Cf[idx] = resid[idx] + v + bias[c];
            }
        }
    }
}

// ---------------- bf16 MFMA GEMM (MoE up) ----------------------------------
// 2-phase double-buffered, BK=64. LDS rows are 128B: swizzle slot ^= (r&7);
// staging: linear dest + inverse-swizzled source (src slot = (l&7)^(l>>3)).
// LDS 2x2x16KB = 64KB. MODE 2: Cb = bf16(gelu(A@B + bias))
template <int MODE>
__global__ void __launch_bounds__(256) mgemm(const unsigned short* __restrict__ A,
                                             const unsigned short* __restrict__ Bt,
                                             const float* __restrict__ bias,
                                             const float* __restrict__ resid,
                                             float* __restrict__ Cf,
                                             unsigned short* __restrict__ Cb,
                                             int N, int K,
                                             const int* __restrict__ perm,
                                             const int* __restrict__ tile_e,
                                             const int* __restrict__ tile_row0,
                                             const int* __restrict__ ntiles) {
    __shared__ __align__(16) short As[2][128][64];
    __shared__ __align__(16) short Bs[2][128][64];

    if ((int)blockIdx.y >= ntiles[0]) return;
    int e = tile_e[blockIdx.y];
    int row0 = tile_row0[blockIdx.y];
    Bt += (size_t)e * N * K;
    bias += (size_t)e * N;
    int n0 = blockIdx.x * 128;

    int tid = threadIdx.x;
    int lane = tid & 63, wid = tid >> 6;
    int wr0 = (wid >> 1) * 64, wc0 = (wid & 1) * 64;
    int lm = lane & 15, q8 = (lane >> 4) * 8;

    int rl = lane >> 3, sl = lane & 7;
    int gsb = (sl ^ rl) << 4;

    const unsigned short* Abase = A + (size_t)row0 * K;
    const unsigned short* Bbase = Bt + (size_t)n0 * K;
    const char* gA = (const char*)(Abase + (size_t)(wid * 32 + rl) * K) + gsb;
    const char* gB = (const char*)(Bbase + (size_t)(wid * 32 + rl) * K) + gsb;

    auto stage = [&](int b, int t) {
        size_t kb = (size_t)t * 128;   // t*64 shorts * 2B
#pragma unroll
        for (int c = 0; c < 4; c++) {
            gload16(gA + (size_t)c * 16 * K + kb, &As[b][wid * 32 + c * 8][0]);
            gload16(gB + (size_t)c * 16 * K + kb, &Bs[b][wid * 32 + c * 8][0]);
        }
    };

    floatx4 acc[4][4];
#pragma unroll
    for (int i = 0; i < 4; i++)
#pragma unroll
        for (int j = 0; j < 4; j++) acc[i][j] = (floatx4){0.f, 0.f, 0.f, 0.f};

    const int NSTEP = K >> 6;
    stage(0, 0);
    __syncthreads();

    int cur = 0;
    for (int t = 0; t < NSTEP; t++) {
        if (t + 1 < NSTEP) stage(cur ^ 1, t + 1);

#pragma unroll
        for (int ks = 0; ks < 2; ks++) {
            short8 af[4], bfr[4];
#pragma unroll
            for (int i = 0; i < 4; i++) {
                int r = wr0 + i * 16 + lm;
                int bo = (ks * 64 + q8 * 2) ^ ((r & 7) << 4);
                af[i] = *(const short8*)((const char*)&As[cur][r][0] + bo);
            }
#pragma unroll
            for (int j = 0; j < 4; j++) {
                int r = wc0 + j * 16 + lm;
                int bo = (ks * 64 + q8 * 2) ^ ((r & 7) << 4);
                bfr[j] = *(const short8*)((const char*)&Bs[cur][r][0] + bo);
            }
#pragma unroll
            for (int i = 0; i < 4; i++)
#pragma unroll
                for (int j = 0; j < 4; j++)
                    acc[i][j] = __builtin_amdgcn_mfma_f32_16x16x32_bf16(af[i], bfr[j], acc[i][j], 0, 0, 0);
        }
        __syncthreads();
        cur ^= 1;
    }

    int q4 = (lane >> 4) * 4;
#pragma unroll
    for (int i = 0; i < 4; i++) {
#pragma unroll
        for (int j = 0; j < 4; j++) {
            int c = n0 + wc0 + j * 16 + lm;
#pragma unroll
            for (int reg = 0; reg < 4; reg++) {
                int rloc = wr0 + i * 16 + q4 + reg;
                float v = acc[i][j][reg];
                if constexpr (MODE == 2) {
                    Cb[(size_t)(row0 + rloc) * N + c] = f2bf(gelu_exact(v + bias[c]));
                } else {
                    int t = perm[row0 + rloc];
                    if (t >= 0) {
                        size_t idx = (size_t)t * N + c;
                        Cf[idx] = resid[idx] + gelu_exact(v + bias[c]);
                    }
                }
            }
        }
    }
}

// ---------------- bf16 MFMA GEMM (MoE down, BN=64 narrow tile) -------------
// R20-validated: 480 blocks, 3 blk/CU; replaced the 85us mgemm<3>.
__global__ void __launch_bounds__(256) dgemm(const unsigned short* __restrict__ A,
                                             const unsigned short* __restrict__ Bt,
                                             const float* __restrict__ bias,
                                             const float* __restrict__ resid,
                                             float* __restrict__ Cf,
                                             int N, int K,
                                             const int* __restrict__ perm,
                                             const int* __restrict__ tile_e,
                                             const int* __restrict__ tile_row0,
                                             const int* __restrict__ ntiles) {
    __shared__ __align__(16) short As[2][128][64];
    __shared__ __align__(16) short Bs[2][64][64];

    if ((int)blockIdx.y >= ntiles[0]) return;
    int e = tile_e[blockIdx.y];
    int row0 = tile_row0[blockIdx.y];
    Bt += (size_t)e * N * K;
    bias += (size_t)e * N;
    int n0 = blockIdx.x * 64;

    int tid = threadIdx.x;
    int lane = tid & 63, wid = tid >> 6;
    int wr0 = (wid >> 1) * 64, wc0 = (wid & 1) * 32;
    int lm = lane & 15, q8 = (lane >> 4) * 8;

    int rl = lane >> 3, sl = lane & 7;
    int gsb = (sl ^ rl) << 4;

    const unsigned short* Abase = A + (size_t)row0 * K;
    const unsigned short* Bbase = Bt + (size_t)n0 * K;
    const char* gA = (const char*)(Abase + (size_t)(wid * 32 + rl) * K) + gsb;
    const char* gB = (const char*)(Bbase + (size_t)(wid * 16 + rl) * K) + gsb;

    auto stage = [&](int b, int t) {
        size_t kb = (size_t)t * 128;   // t*64 shorts * 2B
#pragma unroll
        for (int c = 0; c < 4; c++)    // A: 128 rows, wave owns 32 (4x8)
            gload16(gA + (size_t)c * 16 * K + kb, &As[b][wid * 32 + c * 8][0]);
#pragma unroll
        for (int c = 0; c < 2; c++)    // B: 64 rows, wave owns 16 (2x8)
            gload16(gB + (size_t)c * 16 * K + kb, &Bs[b][wid * 16 + c * 8][0]);
    };

    floatx4 acc[4][2];
#pragma unroll
    for (int i = 0; i < 4; i++)
#pragma unroll
        for (int j = 0; j < 2; j++) acc[i][j] = (floatx4){0.f, 0.f, 0.f, 0.f};

    const int NSTEP = K >> 6;          // 48
    stage(0, 0);
    __syncthreads();

    int cur = 0;
    for (int t = 0; t < NSTEP; t++) {
        if (t + 1 < NSTEP) stage(cur ^ 1, t + 1);

#pragma unroll
        for (int ks = 0; ks < 2; ks++) {
            short8 af[4], bfr[2];
#pragma unroll
            for (int i = 0; i < 4; i++) {
                int r = wr0 + i * 16 + lm;
                int bo = (ks * 64 + q8 * 2) ^ ((r & 7) << 4);
                af[i] = *(const short8*)((const char*)&As[cur][r][0] + bo);
            }
#pragma unroll
            for (int j = 0; j < 2; j++) {
                int r = wc0 + j * 16 + lm;
                int bo = (ks * 64 + q8 * 2) ^ ((r & 7) << 4);
                bfr[j] = *(const short8*)((const char*)&Bs[cur][r][0] + bo);
            }
#pragma unroll
            for (int i = 0; i < 4; i++)
#pragma unroll
                for (int j = 0; j < 2; j++)
                    acc[i][j] = __builtin_amdgcn_mfma_f32_16x16x32_bf16(af[i], bfr[j], acc[i][j], 0, 0, 0);
        }
        __syncthreads();
        cur ^= 1;
    }

    int q4 = (lane >> 4) * 4;
#pragma unroll
    for (int i = 0; i < 4; i++) {
#pragma unroll
        for (int j = 0; j < 2; j++) {
            int c = n0 + wc0 + j * 16 + lm;
#pragma unroll
            for (int reg = 0; reg < 4; reg++) {
                int rloc = wr0 + i * 16 + q4 + reg;
                int t = perm[row0 + rloc];
                if (t >= 0) {
                    size_t idx = (size_t)t * N + c;
                    Cf[idx] = resid[idx] + gelu_exact(acc[i][j][reg] + bias[c]);
                }
            }
        }
    }
}

extern "C" void kernel_launch(void* const* d_in, const int* in_sizes, int n_in,
                              void* d_out, int out_size, void* d_ws, size_t ws_size,
                              hipStream_t stream) {
    const float* x      = (const float*)d_in[0];
    const float* ln1_g  = (const float*)d_in[2];
    const float* ln1_b  = (const float*)d_in[3];
    const float* qkv_w  = (const float*)d_in[4];
    const float* proj_w = (const float*)d_in[5];
    const float* proj_b = (const float*)d_in[6];
    const float* ln2_g  = (const float*)d_in[7];
    const float* ln2_b  = (const float*)d_in[8];
    const float* sw     = (const float*)d_in[9];
    const float* sb     = (const float*)d_in[10];
    const float* w1     = (const float*)d_in[11];
    const float* b1     = (const float*)d_in[12];
    const float* w2     = (const float*)d_in[13];
    const float* b2     = (const float*)d_in[14];
    float* out = (float*)d_out;

    // ---- workspace layout ----
    char* p = (char*)d_ws;
    float*          qkv = (float*)p;
    float*          h   = (float*)p;
    unsigned short* y1  = (unsigned short*)p;
    p += (size_t)T_TOK * 2304 * 4;
    unsigned short* h_hi = (unsigned short*)p; p += (size_t)T_TOK * D_MODEL * 2;
    unsigned short* h_lo = (unsigned short*)p; p += (size_t)T_TOK * D_MODEL * 2;
    unsigned short* o_hi = h_hi;
    unsigned short* o_lo = h_lo;
    float* x1 = (float*)p; p += (size_t)T_TOK * D_MODEL * 4;
    unsigned short* Ag     = (unsigned short*)p;
    unsigned short* qwt_hi = (unsigned short*)p;
    unsigned short* qwt_lo = qwt_hi + (size_t)2304 * 768;
    p += (size_t)MPAD_MAX * D_MODEL * 2;
    unsigned short* pwt_hi = (unsigned short*)p; p += (size_t)768 * 768 * 2;
    unsigned short* pwt_lo = (unsigned short*)p; p += (size_t)768 * 768 * 2;
    unsigned short* w1t = (unsigned short*)p; p += (size_t)E_EXP * 3072 * 768 * 2;
    unsigned short* w2t = (unsigned short*)p; p += (size_t)E_EXP * 768 * 3072 * 2;
    int* routes    = (int*)p;
    int* perm      = routes + T_TOK;
    int* counts    = perm + MPAD_MAX;
    int* cursor    = counts + 8;
    int* pad_base  = cursor + 8;
    int* tile_e    = pad_base + 8;
    int* tile_row0 = tile_e + MAX_TILES;
    int* ntiles    = tile_row0 + MAX_TILES;

    // ---- weight preprocessing ----
    transpose_split<<<dim3(2304 / 32, 768 / 32), 256, 0, stream>>>(qkv_w, qwt_hi, qwt_lo, 768, 2304);
    transpose_split<<<dim3(768 / 32, 768 / 32), 256, 0, stream>>>(proj_w, pwt_hi, pwt_lo, 768, 768);
    transpose_bf16<<<dim3(3072 / 32, 768 / 32, 8), 256, 0, stream>>>(w1, w1t, 768, 3072);
    transpose_bf16<<<dim3(768 / 32, 3072 / 32, 8), 256, 0, stream>>>(w2, w2t, 3072, 768);

    // 1. LN1 -> split bf16 (h_hi, h_lo)
    ln_split<<<T_TOK, 256, 0, stream>>>(x, ln1_g, ln1_b, h_hi, h_lo);
    // 2. QKV (split-bf16 MFMA, BN=64): 36x32 = 1152 blocks
    sgemm<0><<<dim3(2304 / 64, T_TOK / 128), 256, 0, stream>>>(
        h_hi, h_lo, qwt_hi, qwt_lo, nullptr, nullptr, qkv, 2304, 768);
    // 3. Attention (split-bf16 MFMA flash) -> split bf16 o
    attn_mfma<<<dim3(S_SEQ / 64, H_HEADS, B_BATCH), 256, 0, stream>>>(qkv, o_hi, o_lo);
    // 4. Proj + residual (split-bf16 MFMA, BN=64): 12x32 = 384 blocks
    sgemm<1><<<dim3(768 / 64, T_TOK / 128), 256, 0, stream>>>(
        o_hi, o_lo, pwt_hi, pwt_lo, proj_b, x, x1, 768, 768);
    // 5. LN2 -> fp32 h (router path: exact fp32)
    ln_f32<<<T_TOK, 256, 0, stream>>>(x1, ln2_g, ln2_b, h);
    // 6-9. Routing (fp32, unchanged)
    init_kernel<<<(MPAD_MAX + 255) / 256, 256, 0, stream>>>(counts, cursor, perm);
    router_kernel<<<T_TOK, 64, 0, stream>>>(h, sw, sb, routes, counts);
    moe_plan<<<1, 1, 0, stream>>>(counts, pad_base, tile_e, tile_row0, ntiles);
    scatter_kernel<<<T_TOK / 256, 256, 0, stream>>>(routes, pad_base, cursor, perm);
    // 10. Gather routed rows -> packed bf16 A
    gather_bf16<<<MPAD_MAX, 256, 0, stream>>>(h, perm, Ag);
    // 11. MoE up (bf16 MFMA): y1 = bf16(gelu(Ag @ w1t[e] + b1[e]))
    mgemm<2><<<dim3(FF_DIM / 128, MAX_TILES), 256, 0, stream>>>(
        Ag, w1t, b1, nullptr, nullptr, y1, FF_DIM, 768,
        perm, tile_e, tile_row0, ntiles);
    // 12. MoE down + residual scatter, BN=64 tile: 480 blocks
    dgemm<<<dim3(D_MODEL / 64, MAX_TILES), 256, 0, stream>>>(
        y1, w2t, b2, x1, out, D_MODEL, 3072,
        perm, tile_e, tile_row0, ntiles);
}